// Round 1
// baseline (439.182 us; speedup 1.0000x reference)
//
#include <hip/hip_runtime.h>
#include <hip/hip_bf16.h>
#include <math.h>

#define LTOT 36864      // 192*192
#define NH 4
#define NCHUNK 256
#define CHU 144
#define NBUCK 128
#define NSEG 144        // 36864 / 256
#define HW_ 192

typedef unsigned int u32;
typedef unsigned short u16;

// ---------------- conv: 3x3 (32->8, pad1) + 1x1 (32->32) fused ----------------
__global__ __launch_bounds__(256) void k_conv(const float* __restrict__ x,
    const float* __restrict__ wm, const float* __restrict__ bm,
    const float* __restrict__ wa, const float* __restrict__ ba,
    float* __restrict__ xe, float* __restrict__ ye)
{
  __shared__ float xs[32*324];   // 32 ch x 18x18 halo tile
  const int t = threadIdx.x;
  const int bx = blockIdx.x, by = blockIdx.y;
  for (int idx=t; idx<32*324; idx+=256){
    int ci = idx/324; int rem = idx-ci*324;
    int iy = rem/18;  int ix = rem-iy*18;
    int gy = by*16+iy-1, gx = bx*16+ix-1;
    float v = 0.f;
    if (gy>=0 && gy<HW_ && gx>=0 && gx<HW_) v = x[ci*LTOT + gy*HW_ + gx];
    xs[idx] = v;
  }
  __syncthreads();
  const int tx = t & 15, ty = t >> 4;
  float accm[8];
  #pragma unroll
  for (int co=0;co<8;co++) accm[co] = bm[co];
  float acca[32];
  #pragma unroll
  for (int co=0;co<32;co++) acca[co] = ba[co];
  const float* xp0 = xs + ty*18 + tx;
  for (int ci=0; ci<32; ci++){
    const float* xp = xp0 + ci*324;
    float x00=xp[0],  x01=xp[1],  x02=xp[2];
    float x10=xp[18], x11=xp[19], x12=xp[20];
    float x20=xp[36], x21=xp[37], x22=xp[38];
    #pragma unroll
    for (int co=0;co<8;co++){
      const float* w = wm + co*288 + ci*9;  // wm[co][ci][ky][kx]
      accm[co] += x00*w[0]+x01*w[1]+x02*w[2]
                + x10*w[3]+x11*w[4]+x12*w[5]
                + x20*w[6]+x21*w[7]+x22*w[8];
    }
    #pragma unroll
    for (int co=0;co<32;co++) acca[co] += x11 * wa[co*32+ci];
  }
  const int gx = bx*16+tx, gy = by*16+ty;
  const int l = gy*HW_+gx;
  #pragma unroll
  for (int co=0;co<8;co++)  xe[l*8+co]  = accm[co];
  #pragma unroll
  for (int co=0;co<32;co++) ye[l*32+co] = acca[co];
}

// ---------------- LSH hash codes ----------------
__global__ __launch_bounds__(256) void k_hash(const float* __restrict__ xe,
    const float* __restrict__ rot, int* __restrict__ code)
{
  int l = blockIdx.x*256 + threadIdx.x;
  const float4* qp = (const float4*)(xe + l*8);
  float4 qa = qp[0], qb = qp[1];
  #pragma unroll
  for (int h=0; h<NH; h++){
    float best = -INFINITY; int bi = 0;
    float worst = INFINITY; int wi = 0;
    for (int i=0; i<64; i++){
      const float* rp = rot + h*64 + i;   // rot[f*256 + h*64 + i]
      float v = qa.x*rp[0]    + qa.y*rp[256]  + qa.z*rp[512]  + qa.w*rp[768]
              + qb.x*rp[1024] + qb.y*rp[1280] + qb.z*rp[1536] + qb.w*rp[1792];
      if (v > best)  { best  = v; bi = i; }
      if (v < worst) { worst = v; wi = i; }
    }
    // argmax over concat([r, -r]): second half wins only on strict >
    int c = (-worst > best) ? (64+wi) : bi;
    code[h*LTOT + l] = c;
  }
}

// ---------------- stable counting sort: local ranks + histograms ----------------
__global__ __launch_bounds__(256) void k_rank(const int* __restrict__ code,
    int* __restrict__ lrank, int* __restrict__ hist)
{
  const int h = blockIdx.y, seg = blockIdx.x, t = threadIdx.x;
  const int l = seg*256 + t;
  __shared__ int lc[256];
  __shared__ int lh[NBUCK];
  int c = code[h*LTOT + l];
  lc[t] = c;
  if (t < NBUCK) lh[t] = 0;
  __syncthreads();
  int r = 0;
  for (int j=0; j<t; j++) r += (lc[j] == c) ? 1 : 0;
  atomicAdd(&lh[c], 1);
  __syncthreads();
  lrank[h*LTOT + l] = r;
  if (t < NBUCK) hist[(h*NSEG+seg)*NBUCK + t] = lh[t];
}

// ---------------- bucket/segment prefix scan ----------------
__global__ __launch_bounds__(128) void k_scan(const int* __restrict__ hist,
    int* __restrict__ segoff)
{
  const int h = blockIdx.x, b = threadIdx.x;
  __shared__ int tot[NBUCK];
  __shared__ int base_s[NBUCK];
  int run = 0;
  #pragma unroll 4
  for (int s=0; s<NSEG; s++) run += hist[(h*NSEG+s)*NBUCK + b];
  tot[b] = run;
  __syncthreads();
  if (b == 0){
    int acc = 0;
    for (int i=0; i<NBUCK; i++){ base_s[i] = acc; acc += tot[i]; }
  }
  __syncthreads();
  int run2 = base_s[b];
  for (int s=0; s<NSEG; s++){
    segoff[(h*NSEG+s)*NBUCK + b] = run2;
    run2 += hist[(h*NSEG+s)*NBUCK + b];
  }
}

// ---------------- scatter: sorted position & inverse rank ----------------
__global__ __launch_bounds__(256) void k_scatter(const int* __restrict__ code,
    const int* __restrict__ lrank, const int* __restrict__ segoff,
    int* __restrict__ spos, int* __restrict__ rankof)
{
  const int h = blockIdx.y, seg = blockIdx.x, t = threadIdx.x;
  const int l = seg*256 + t;
  int c = code[h*LTOT + l];
  int r = segoff[(h*NSEG+seg)*NBUCK + c] + lrank[h*LTOT + l];
  spos[h*LTOT + r] = l;
  rankof[h*LTOT + l] = r;
}

// ---------------- chunked attention ----------------
__global__ __launch_bounds__(192) void k_attn(const float* __restrict__ xe,
    const float* __restrict__ ye, const int* __restrict__ spos,
    float* __restrict__ ret_s, float* __restrict__ bs_s)
{
  __shared__ __align__(16) float xq[CHU*8];     // raw query rows (chunk k)
  __shared__ __align__(16) float xm[432*8];     // normalized key rows (k-1,k,k+1 order: self,back,fwd)
  __shared__ __align__(16) u16   ym[432*32];    // value rows, bf16
  const int t = threadIdx.x;
  const int k = blockIdx.x, h = blockIdx.y;

  for (int j=t; j<432; j+=192){
    int region = j/CHU;            // 0=self, 1=back(k-1), 2=fwd(k+1)
    int i = j - region*CHU;
    int ck = k + ((region==1)? -1 : (region==2)? 1 : 0);
    ck &= (NCHUNK-1);
    int pos = spos[h*LTOT + ck*CHU + i];
    const float4* xr = (const float4*)(xe + pos*8);
    float4 a = xr[0], b = xr[1];
    if (region==0){
      float4* q = (float4*)(xq + i*8);
      q[0]=a; q[1]=b;
    }
    float n2 = a.x*a.x+a.y*a.y+a.z*a.z+a.w*a.w
             + b.x*b.x+b.y*b.y+b.z*b.z+b.w*b.w;
    float sc = 1.0f / fmaxf(sqrtf(n2), 5e-5f);
    float4* mp = (float4*)(xm + j*8);
    mp[0] = make_float4(a.x*sc,a.y*sc,a.z*sc,a.w*sc);
    mp[1] = make_float4(b.x*sc,b.y*sc,b.z*sc,b.w*sc);
    const float2* yr = (const float2*)(ye + pos*32);
    u32* yd = (u32*)(ym + j*32);
    #pragma unroll
    for (int e=0;e<16;e++){
      float2 yv = yr[e];
      u32 ua = __float_as_uint(yv.x), ub = __float_as_uint(yv.y);
      ua = (ua + 0x7fffu + ((ua>>16)&1u)) >> 16;   // RTNE to bf16
      ub = (ub + 0x7fffu + ((ub>>16)&1u)) >> 16;
      yd[e] = ua | (ub<<16);
    }
  }
  __syncthreads();

  if (t < CHU){
    const float4* qp = (const float4*)(xq + t*8);
    float4 qa = qp[0], qb = qp[1];
    // pass 1: row max
    float m = -INFINITY;
    for (int j=0;j<432;j++){
      const float4* xr = (const float4*)(xm + j*8);
      float4 a = xr[0], b = xr[1];
      float d = qa.x*a.x+qa.y*a.y+qa.z*a.z+qa.w*a.w
              + qb.x*b.x+qb.y*b.y+qb.z*b.z+qb.w*b.w;
      m = fmaxf(m, d);
    }
    // pass 2: exp-sum + weighted value accumulation
    float s = 0.f;
    float acc[32];
    #pragma unroll
    for (int e=0;e<32;e++) acc[e]=0.f;
    for (int j=0;j<432;j++){
      const float4* xr = (const float4*)(xm + j*8);
      float4 a = xr[0], b = xr[1];
      float d = qa.x*a.x+qa.y*a.y+qa.z*a.z+qa.w*a.w
              + qb.x*b.x+qb.y*b.y+qb.z*b.z+qb.w*b.w;
      float p = __expf(d - m);
      s += p;
      const uint4* yp = (const uint4*)(ym + j*32);
      #pragma unroll
      for (int q4=0;q4<4;q4++){
        uint4 w = yp[q4];
        acc[q4*8+0] += p*__uint_as_float(w.x<<16);
        acc[q4*8+1] += p*__uint_as_float(w.x&0xffff0000u);
        acc[q4*8+2] += p*__uint_as_float(w.y<<16);
        acc[q4*8+3] += p*__uint_as_float(w.y&0xffff0000u);
        acc[q4*8+4] += p*__uint_as_float(w.z<<16);
        acc[q4*8+5] += p*__uint_as_float(w.z&0xffff0000u);
        acc[q4*8+6] += p*__uint_as_float(w.w<<16);
        acc[q4*8+7] += p*__uint_as_float(w.w&0xffff0000u);
      }
    }
    float inv = 1.0f/s;
    int row = h*LTOT + k*CHU + t;
    bs_s[row] = m + __logf(s);
    float4* rp = (float4*)(ret_s + (size_t)row*32);
    #pragma unroll
    for (int q4=0;q4<8;q4++)
      rp[q4] = make_float4(acc[q4*4]*inv, acc[q4*4+1]*inv,
                           acc[q4*4+2]*inv, acc[q4*4+3]*inv);
  }
}

// ---------------- unsort + cross-hash softmax + residual ----------------
__global__ __launch_bounds__(256) void k_final(const float* __restrict__ x,
    const int* __restrict__ rankof, const float* __restrict__ ret_s,
    const float* __restrict__ bs_s, float* __restrict__ out)
{
  const int l = blockIdx.x*256 + threadIdx.x;
  int r[NH]; float bs[NH];
  #pragma unroll
  for (int h=0;h<NH;h++){ r[h] = rankof[h*LTOT + l]; bs[h] = bs_s[h*LTOT + r[h]]; }
  float m = fmaxf(fmaxf(bs[0],bs[1]), fmaxf(bs[2],bs[3]));
  float p[NH]; float s = 0.f;
  #pragma unroll
  for (int h=0;h<NH;h++){ p[h] = __expf(bs[h]-m); s += p[h]; }
  float inv = 1.0f/s;
  float o[32];
  #pragma unroll
  for (int e=0;e<32;e++) o[e]=0.f;
  #pragma unroll
  for (int h=0;h<NH;h++){
    const float4* rp = (const float4*)(ret_s + (size_t)(h*LTOT + r[h])*32);
    float w = p[h]*inv;
    #pragma unroll
    for (int q=0;q<8;q++){
      float4 v = rp[q];
      o[q*4+0] += w*v.x; o[q*4+1] += w*v.y; o[q*4+2] += w*v.z; o[q*4+3] += w*v.w;
    }
  }
  #pragma unroll
  for (int e=0;e<32;e++) out[e*LTOT + l] = o[e] + x[e*LTOT + l];
}

extern "C" void kernel_launch(void* const* d_in, const int* in_sizes, int n_in,
                              void* d_out, int out_size, void* d_ws, size_t ws_size,
                              hipStream_t stream)
{
  const float* x   = (const float*)d_in[0];
  const float* wm  = (const float*)d_in[1];
  const float* bm  = (const float*)d_in[2];
  const float* wa  = (const float*)d_in[3];
  const float* ba  = (const float*)d_in[4];
  const float* rot = (const float*)d_in[5];
  float* out = (float*)d_out;

  char* ws = (char*)d_ws;
  size_t off = 0;
  auto alloc = [&](size_t bytes)->void*{
    void* p = ws + off;
    off = (off + bytes + 255) & ~(size_t)255;
    return p;
  };
  float* xe     = (float*)alloc((size_t)LTOT*8*4);
  float* ye     = (float*)alloc((size_t)LTOT*32*4);
  int*   code   = (int*)  alloc((size_t)NH*LTOT*4);
  int*   lrank  = (int*)  alloc((size_t)NH*LTOT*4);
  int*   hist   = (int*)  alloc((size_t)NH*NSEG*NBUCK*4);
  int*   segoff = (int*)  alloc((size_t)NH*NSEG*NBUCK*4);
  int*   spos   = (int*)  alloc((size_t)NH*LTOT*4);
  int*   rankof = (int*)  alloc((size_t)NH*LTOT*4);
  float* bs_s   = (float*)alloc((size_t)NH*LTOT*4);
  float* ret_s  = (float*)alloc((size_t)NH*LTOT*32*4);

  hipLaunchKernelGGL(k_conv,    dim3(12,12),      dim3(256), 0, stream, x, wm, bm, wa, ba, xe, ye);
  hipLaunchKernelGGL(k_hash,    dim3(144),        dim3(256), 0, stream, xe, rot, code);
  hipLaunchKernelGGL(k_rank,    dim3(NSEG,NH),    dim3(256), 0, stream, code, lrank, hist);
  hipLaunchKernelGGL(k_scan,    dim3(NH),         dim3(128), 0, stream, hist, segoff);
  hipLaunchKernelGGL(k_scatter, dim3(NSEG,NH),    dim3(256), 0, stream, code, lrank, segoff, spos, rankof);
  hipLaunchKernelGGL(k_attn,    dim3(NCHUNK,NH),  dim3(192), 0, stream, xe, ye, spos, ret_s, bs_s);
  hipLaunchKernelGGL(k_final,   dim3(144),        dim3(256), 0, stream, x, rankof, ret_s, bs_s, out);
}

// Round 2
// 188.866 us; speedup vs baseline: 2.3254x; 2.3254x over previous
//
#include <hip/hip_runtime.h>
#include <hip/hip_bf16.h>
#include <math.h>

#define LTOT 36864      // 192*192
#define NH 4
#define NCHUNK 256
#define CHU 144
#define NBUCK 128
#define NSEG 144        // 36864 / 256
#define HW_ 192
#define VTS 436         // VT lds row stride (u16 units) — odd*4 to spread banks

typedef unsigned int u32;
typedef unsigned short u16;
typedef __attribute__((ext_vector_type(4))) short short4v;
typedef __attribute__((ext_vector_type(4))) float f32x4;

__device__ __forceinline__ u32 f2bf(float f){
  u32 u = __float_as_uint(f);
  return (u + 0x7fffu + ((u >> 16) & 1u)) >> 16;   // RTNE
}

// ---------------- conv: 3x3 (32->8, pad1) + 1x1 (32->32) fused ----------------
__global__ __launch_bounds__(256) void k_conv(const float* __restrict__ x,
    const float* __restrict__ wm, const float* __restrict__ bm,
    const float* __restrict__ wa, const float* __restrict__ ba,
    float* __restrict__ xe, float* __restrict__ ye)
{
  __shared__ float xs[32*324];   // 32 ch x 18x18 halo tile
  const int t = threadIdx.x;
  const int bx = blockIdx.x, by = blockIdx.y;
  for (int idx=t; idx<32*324; idx+=256){
    int ci = idx/324; int rem = idx-ci*324;
    int iy = rem/18;  int ix = rem-iy*18;
    int gy = by*16+iy-1, gx = bx*16+ix-1;
    float v = 0.f;
    if (gy>=0 && gy<HW_ && gx>=0 && gx<HW_) v = x[ci*LTOT + gy*HW_ + gx];
    xs[idx] = v;
  }
  __syncthreads();
  const int tx = t & 15, ty = t >> 4;
  float accm[8];
  #pragma unroll
  for (int co=0;co<8;co++) accm[co] = bm[co];
  float acca[32];
  #pragma unroll
  for (int co=0;co<32;co++) acca[co] = ba[co];
  const float* xp0 = xs + ty*18 + tx;
  for (int ci=0; ci<32; ci++){
    const float* xp = xp0 + ci*324;
    float x00=xp[0],  x01=xp[1],  x02=xp[2];
    float x10=xp[18], x11=xp[19], x12=xp[20];
    float x20=xp[36], x21=xp[37], x22=xp[38];
    #pragma unroll
    for (int co=0;co<8;co++){
      const float* w = wm + co*288 + ci*9;
      accm[co] += x00*w[0]+x01*w[1]+x02*w[2]
                + x10*w[3]+x11*w[4]+x12*w[5]
                + x20*w[6]+x21*w[7]+x22*w[8];
    }
    #pragma unroll
    for (int co=0;co<32;co++) acca[co] += x11 * wa[co*32+ci];
  }
  const int gx = bx*16+tx, gy = by*16+ty;
  const int l = gy*HW_+gx;
  #pragma unroll
  for (int co=0;co<8;co++)  xe[l*8+co]  = accm[co];
  #pragma unroll
  for (int co=0;co<32;co++) ye[l*32+co] = acca[co];
}

// ---------------- LSH hash codes (fp32 exact; rot reads are wave-uniform -> s_load) ----------------
__global__ __launch_bounds__(256) void k_hash(const float* __restrict__ xe,
    const float* __restrict__ rot, int* __restrict__ code)
{
  int l = blockIdx.x*256 + threadIdx.x;
  const int h = blockIdx.y;
  const float4* qp = (const float4*)(xe + l*8);
  float4 qa = qp[0], qb = qp[1];
  float best = -INFINITY; int bi = 0;
  float worst = INFINITY; int wi = 0;
  for (int i=0; i<64; i++){
    const float* rp = rot + h*64 + i;   // rot[f*256 + h*64 + i]
    float v = qa.x*rp[0]    + qa.y*rp[256]  + qa.z*rp[512]  + qa.w*rp[768]
            + qb.x*rp[1024] + qb.y*rp[1280] + qb.z*rp[1536] + qb.w*rp[1792];
    if (v > best)  { best  = v; bi = i; }
    if (v < worst) { worst = v; wi = i; }
  }
  int c = (-worst > best) ? (64+wi) : bi;
  code[h*LTOT + l] = c;
}

// ---------------- stable counting sort: local ranks + histograms ----------------
__global__ __launch_bounds__(256) void k_rank(const int* __restrict__ code,
    int* __restrict__ lrank, int* __restrict__ hist)
{
  const int h = blockIdx.y, seg = blockIdx.x, t = threadIdx.x;
  const int l = seg*256 + t;
  __shared__ int lc[256];
  __shared__ int lh[NBUCK];
  int c = code[h*LTOT + l];
  lc[t] = c;
  if (t < NBUCK) lh[t] = 0;
  __syncthreads();
  int r = 0;
  for (int j=0; j<t; j++) r += (lc[j] == c) ? 1 : 0;
  atomicAdd(&lh[c], 1);
  __syncthreads();
  lrank[h*LTOT + l] = r;
  if (t < NBUCK) hist[(h*NSEG+seg)*NBUCK + t] = lh[t];
}

// ---------------- bucket/segment prefix scan ----------------
__global__ __launch_bounds__(128) void k_scan(const int* __restrict__ hist,
    int* __restrict__ segoff)
{
  const int h = blockIdx.x, b = threadIdx.x;
  __shared__ int tot[NBUCK];
  __shared__ int base_s[NBUCK];
  int run = 0;
  #pragma unroll 4
  for (int s=0; s<NSEG; s++) run += hist[(h*NSEG+s)*NBUCK + b];
  tot[b] = run;
  __syncthreads();
  if (b == 0){
    int acc = 0;
    for (int i=0; i<NBUCK; i++){ base_s[i] = acc; acc += tot[i]; }
  }
  __syncthreads();
  int run2 = base_s[b];
  for (int s=0; s<NSEG; s++){
    segoff[(h*NSEG+s)*NBUCK + b] = run2;
    run2 += hist[(h*NSEG+s)*NBUCK + b];
  }
}

// ---------------- scatter: sorted position & inverse rank ----------------
__global__ __launch_bounds__(256) void k_scatter(const int* __restrict__ code,
    const int* __restrict__ lrank, const int* __restrict__ segoff,
    int* __restrict__ spos, int* __restrict__ rankof)
{
  const int h = blockIdx.y, seg = blockIdx.x, t = threadIdx.x;
  const int l = seg*256 + t;
  int c = code[h*LTOT + l];
  int r = segoff[(h*NSEG+seg)*NBUCK + c] + lrank[h*LTOT + l];
  spos[h*LTOT + r] = l;
  rankof[h*LTOT + l] = r;
}

// ---------------- chunked attention, MFMA flash-style ----------------
// Per block (h,k): Q 144x8 raw, K 432x8 normalized, V 432x32 (all bf16).
// S^T = K.Q^T via mfma_16x16x16_bf16 (feats 8..15 zero-padded).
// C-layout of S^T (col=lane&15=query, row=quad*4+reg=key) == B-operand layout
// of P^T for O^T = V^T.P^T  -> no cross-lane transpose, only fp32->bf16 pack.
__global__ __launch_bounds__(576) void k_attn(const float* __restrict__ xe,
    const float* __restrict__ ye, const int* __restrict__ spos,
    float* __restrict__ ret_s, float* __restrict__ bs_s)
{
  __shared__ int spos_l[432];
  __shared__ __align__(16) u16 Klds[432*8];   // key-major, 8 bf16 feats (16 B rows)
  __shared__ __align__(16) u16 Qlds[144*8];   // raw queries
  __shared__ __align__(16) u16 VT[32*VTS];    // V^T: [e][key], stride VTS

  const int t = threadIdx.x;
  const int k = blockIdx.x, h = blockIdx.y;

  // phase 1: gather keys/queries, normalize K, pack bf16
  if (t < 432){
    int region = (t < CHU) ? 0 : (t < 2*CHU) ? 1 : 2;
    int i = t - region*CHU;
    int ck = (k + ((region==1)? -1 : (region==2)? 1 : 0)) & (NCHUNK-1);
    int pos = spos[h*LTOT + ck*CHU + i];
    spos_l[t] = pos;
    const float4* xr = (const float4*)(xe + pos*8);
    float4 a = xr[0], b = xr[1];
    if (region==0){
      uint4 qpk;
      qpk.x = f2bf(a.x) | (f2bf(a.y)<<16);
      qpk.y = f2bf(a.z) | (f2bf(a.w)<<16);
      qpk.z = f2bf(b.x) | (f2bf(b.y)<<16);
      qpk.w = f2bf(b.z) | (f2bf(b.w)<<16);
      *(uint4*)(Qlds + t*8) = qpk;
    }
    float n2 = a.x*a.x+a.y*a.y+a.z*a.z+a.w*a.w
             + b.x*b.x+b.y*b.y+b.z*b.z+b.w*b.w;
    float sc = 1.0f / fmaxf(sqrtf(n2), 5e-5f);
    uint4 kpk;
    kpk.x = f2bf(a.x*sc) | (f2bf(a.y*sc)<<16);
    kpk.y = f2bf(a.z*sc) | (f2bf(a.w*sc)<<16);
    kpk.z = f2bf(b.x*sc) | (f2bf(b.y*sc)<<16);
    kpk.w = f2bf(b.z*sc) | (f2bf(b.w*sc)<<16);
    *(uint4*)(Klds + t*8) = kpk;
  }
  __syncthreads();

  // phase 2: stage V^T (bf16), two keys per thread -> u32 writes
  if (t < 216){
    int posA = spos_l[2*t], posB = spos_l[2*t+1];
    const float4* ya = (const float4*)(ye + posA*32);
    const float4* yb = (const float4*)(ye + posB*32);
    #pragma unroll
    for (int e4=0; e4<8; e4++){
      float4 va = ya[e4], vb = yb[e4];
      *(u32*)&VT[(e4*4+0)*VTS + 2*t] = f2bf(va.x) | (f2bf(vb.x)<<16);
      *(u32*)&VT[(e4*4+1)*VTS + 2*t] = f2bf(va.y) | (f2bf(vb.y)<<16);
      *(u32*)&VT[(e4*4+2)*VTS + 2*t] = f2bf(va.z) | (f2bf(vb.z)<<16);
      *(u32*)&VT[(e4*4+3)*VTS + 2*t] = f2bf(va.w) | (f2bf(vb.w)<<16);
    }
  }
  __syncthreads();

  // main: wave wv owns query tile wv (16 queries); flash over 27 key tiles
  const int lane = t & 63;
  const int wv = t >> 6;          // 0..8
  const int q = lane & 15;        // query (B/D cols) / e (PV A rows)
  const int quad = lane >> 4;     // 0..3

  const short4v zs = {0,0,0,0};
  // B operand: Q^T[k=feat][n=query]; quads 0,1 hold feats 0..7, rest zero
  short4v bq = zs;
  if (quad < 2) bq = *(const short4v*)(Qlds + (wv*16+q)*8 + quad*4);

  f32x4 o0 = {0.f,0.f,0.f,0.f}, o1 = {0.f,0.f,0.f,0.f};
  float m = -INFINITY, s = 0.f;

  for (int kt=0; kt<27; kt++){
    // A operand: K[m=key][k=feat]
    short4v av = zs;
    if (quad < 2) av = *(const short4v*)(Klds + (kt*16+q)*8 + quad*4);
    f32x4 zc = {0.f,0.f,0.f,0.f};
    f32x4 st = __builtin_amdgcn_mfma_f32_16x16x16bf16_1k(av, bq, zc, 0,0,0);

    // per-query max across this tile's 16 keys (4 regs x 4 quads)
    float tm = fmaxf(fmaxf(st[0],st[1]), fmaxf(st[2],st[3]));
    tm = fmaxf(tm, __shfl_xor(tm, 16));
    tm = fmaxf(tm, __shfl_xor(tm, 32));
    float mnew = fmaxf(m, tm);
    float fac = __expf(m - mnew);
    m = mnew;

    float p0 = __expf(st[0]-mnew), p1 = __expf(st[1]-mnew);
    float p2 = __expf(st[2]-mnew), p3 = __expf(st[3]-mnew);
    s = s*fac + (p0+p1+p2+p3);

    union { u32 u[2]; short4v s4; } pk;
    pk.u[0] = f2bf(p0) | (f2bf(p1)<<16);
    pk.u[1] = f2bf(p2) | (f2bf(p3)<<16);
    // pad upper half of B-frag K dim? 16x16x16: exactly 4 bf16 -> done.

    o0[0]*=fac; o0[1]*=fac; o0[2]*=fac; o0[3]*=fac;
    o1[0]*=fac; o1[1]*=fac; o1[2]*=fac; o1[3]*=fac;

    short4v va0 = *(const short4v*)(&VT[ q      *VTS + kt*16 + quad*4]);
    short4v va1 = *(const short4v*)(&VT[(q+16)  *VTS + kt*16 + quad*4]);
    o0 = __builtin_amdgcn_mfma_f32_16x16x16bf16_1k(va0, pk.s4, o0, 0,0,0);
    o1 = __builtin_amdgcn_mfma_f32_16x16x16bf16_1k(va1, pk.s4, o1, 0,0,0);
  }

  // reduce denominator across quads
  float stot = s;
  stot += __shfl_xor(stot, 16);
  stot += __shfl_xor(stot, 32);
  float inv = 1.0f / stot;

  const int row = h*LTOT + k*CHU + wv*16 + q;
  float* rp = ret_s + (size_t)row*32;
  #pragma unroll
  for (int r=0; r<4; r++){
    rp[quad*4+r]      = o0[r]*inv;
    rp[16+quad*4+r]   = o1[r]*inv;
  }
  if (lane < 16)
    bs_s[h*LTOT + k*CHU + wv*16 + lane] = m + __logf(stot);
}

// ---------------- unsort + cross-hash softmax + residual ----------------
__global__ __launch_bounds__(128) void k_final(const float* __restrict__ x,
    const int* __restrict__ rankof, const float* __restrict__ ret_s,
    const float* __restrict__ bs_s, float* __restrict__ out)
{
  const int l = blockIdx.x*128 + threadIdx.x;
  int r[NH]; float bs[NH];
  #pragma unroll
  for (int h=0;h<NH;h++){ r[h] = rankof[h*LTOT + l]; bs[h] = bs_s[h*LTOT + r[h]]; }
  float m = fmaxf(fmaxf(bs[0],bs[1]), fmaxf(bs[2],bs[3]));
  float p[NH]; float s = 0.f;
  #pragma unroll
  for (int h=0;h<NH;h++){ p[h] = __expf(bs[h]-m); s += p[h]; }
  float inv = 1.0f/s;
  float o[32];
  #pragma unroll
  for (int e=0;e<32;e++) o[e]=0.f;
  #pragma unroll
  for (int h=0;h<NH;h++){
    const float4* rp = (const float4*)(ret_s + (size_t)(h*LTOT + r[h])*32);
    float w = p[h]*inv;
    #pragma unroll
    for (int qq=0;qq<8;qq++){
      float4 v = rp[qq];
      o[qq*4+0] += w*v.x; o[qq*4+1] += w*v.y; o[qq*4+2] += w*v.z; o[qq*4+3] += w*v.w;
    }
  }
  #pragma unroll
  for (int e=0;e<32;e++) out[e*LTOT + l] = o[e] + x[e*LTOT + l];
}

extern "C" void kernel_launch(void* const* d_in, const int* in_sizes, int n_in,
                              void* d_out, int out_size, void* d_ws, size_t ws_size,
                              hipStream_t stream)
{
  const float* x   = (const float*)d_in[0];
  const float* wm  = (const float*)d_in[1];
  const float* bm  = (const float*)d_in[2];
  const float* wa  = (const float*)d_in[3];
  const float* ba  = (const float*)d_in[4];
  const float* rot = (const float*)d_in[5];
  float* out = (float*)d_out;

  char* ws = (char*)d_ws;
  size_t off = 0;
  auto alloc = [&](size_t bytes)->void*{
    void* p = ws + off;
    off = (off + bytes + 255) & ~(size_t)255;
    return p;
  };
  float* xe     = (float*)alloc((size_t)LTOT*8*4);
  float* ye     = (float*)alloc((size_t)LTOT*32*4);
  int*   code   = (int*)  alloc((size_t)NH*LTOT*4);
  int*   lrank  = (int*)  alloc((size_t)NH*LTOT*4);
  int*   hist   = (int*)  alloc((size_t)NH*NSEG*NBUCK*4);
  int*   segoff = (int*)  alloc((size_t)NH*NSEG*NBUCK*4);
  int*   spos   = (int*)  alloc((size_t)NH*LTOT*4);
  int*   rankof = (int*)  alloc((size_t)NH*LTOT*4);
  float* bs_s   = (float*)alloc((size_t)NH*LTOT*4);
  float* ret_s  = (float*)alloc((size_t)NH*LTOT*32*4);

  hipLaunchKernelGGL(k_conv,    dim3(12,12),      dim3(256), 0, stream, x, wm, bm, wa, ba, xe, ye);
  hipLaunchKernelGGL(k_hash,    dim3(144,NH),     dim3(256), 0, stream, xe, rot, code);
  hipLaunchKernelGGL(k_rank,    dim3(NSEG,NH),    dim3(256), 0, stream, code, lrank, hist);
  hipLaunchKernelGGL(k_scan,    dim3(NH),         dim3(128), 0, stream, hist, segoff);
  hipLaunchKernelGGL(k_scatter, dim3(NSEG,NH),    dim3(256), 0, stream, code, lrank, segoff, spos, rankof);
  hipLaunchKernelGGL(k_attn,    dim3(NCHUNK,NH),  dim3(576), 0, stream, xe, ye, spos, ret_s, bs_s);
  hipLaunchKernelGGL(k_final,   dim3(288),        dim3(128), 0, stream, x, rankof, ret_s, bs_s, out);
}

// Round 3
// 184.409 us; speedup vs baseline: 2.3816x; 1.0242x over previous
//
#include <hip/hip_runtime.h>
#include <hip/hip_bf16.h>
#include <math.h>

#define LTOT 36864      // 192*192
#define NH 4
#define NCHUNK 256
#define CHU 144
#define NBUCK 128
#define NSEG 144        // 36864 / 256
#define HW_ 192
#define VTS 436         // VT lds row stride (u16 units)

typedef unsigned int u32;
typedef unsigned short u16;
typedef unsigned long long u64;
typedef __attribute__((ext_vector_type(4))) short short4v;
typedef __attribute__((ext_vector_type(4))) float f32x4;

__device__ __forceinline__ u32 pkbf(float a, float b){
  union { __hip_bfloat162 h2; u32 u; } cv;
  cv.h2 = __float22bfloat162_rn(float2{a,b});
  return cv.u;
}

// ---------------- conv, z-split: z=0 -> 3x3 (32->8, pad1); z=1..4 -> 1x1 (8ch each) ----------------
__global__ __launch_bounds__(256) void k_conv(const float* __restrict__ x,
    const float* __restrict__ wm, const float* __restrict__ bm,
    const float* __restrict__ wa, const float* __restrict__ ba,
    float* __restrict__ xe, float* __restrict__ ye)
{
  __shared__ float xs[32*324];   // only used by z==0 blocks
  const int t = threadIdx.x;
  const int bx = blockIdx.x, by = blockIdx.y, z = blockIdx.z;
  const int tx = t & 15, ty = t >> 4;
  const int gx = bx*16+tx, gy = by*16+ty;
  const int l = gy*HW_+gx;

  if (z == 0){
    for (int idx=t; idx<32*324; idx+=256){
      int ci = idx/324; int rem = idx-ci*324;
      int iy = rem/18;  int ix = rem-iy*18;
      int yy = by*16+iy-1, xx = bx*16+ix-1;
      float v = 0.f;
      if (yy>=0 && yy<HW_ && xx>=0 && xx<HW_) v = x[ci*LTOT + yy*HW_ + xx];
      xs[idx] = v;
    }
    __syncthreads();
    float accm[8];
    #pragma unroll
    for (int co=0;co<8;co++) accm[co] = bm[co];
    const float* xp0 = xs + ty*18 + tx;
    for (int ci=0; ci<32; ci++){
      const float* xp = xp0 + ci*324;
      float x00=xp[0],  x01=xp[1],  x02=xp[2];
      float x10=xp[18], x11=xp[19], x12=xp[20];
      float x20=xp[36], x21=xp[37], x22=xp[38];
      #pragma unroll
      for (int co=0;co<8;co++){
        const float* w = wm + co*288 + ci*9;
        accm[co] += x00*w[0]+x01*w[1]+x02*w[2]
                  + x10*w[3]+x11*w[4]+x12*w[5]
                  + x20*w[6]+x21*w[7]+x22*w[8];
      }
    }
    float4* xp = (float4*)(xe + l*8);
    xp[0] = make_float4(accm[0],accm[1],accm[2],accm[3]);
    xp[1] = make_float4(accm[4],accm[5],accm[6],accm[7]);
  } else {
    const int cb = (z-1)*8;
    float acc[8];
    #pragma unroll
    for (int co=0;co<8;co++) acc[co] = ba[cb+co];
    #pragma unroll 4
    for (int ci=0; ci<32; ci++){
      float xv = x[ci*LTOT + l];
      #pragma unroll
      for (int co=0;co<8;co++) acc[co] += xv * wa[(cb+co)*32 + ci];
    }
    float4* yp = (float4*)(ye + l*32 + cb);
    yp[0] = make_float4(acc[0],acc[1],acc[2],acc[3]);
    yp[1] = make_float4(acc[4],acc[5],acc[6],acc[7]);
  }
}

// ---------------- hash + stable local rank (merged), ballot-based ----------------
__global__ __launch_bounds__(256) void k_hashrank(const float* __restrict__ xe,
    const float* __restrict__ rot, int* __restrict__ code,
    int* __restrict__ lrank, int* __restrict__ hist)
{
  const int h = blockIdx.y, seg = blockIdx.x, t = threadIdx.x;
  const int l = seg*256 + t;
  const float4* qp = (const float4*)(xe + l*8);
  float4 qa = qp[0], qb = qp[1];
  float best = -INFINITY; int bi = 0;
  float worst = INFINITY; int wi = 0;
  for (int i=0; i<64; i++){
    const float* rp = rot + h*64 + i;   // rot[f*256 + h*64 + i]
    float v = qa.x*rp[0]    + qa.y*rp[256]  + qa.z*rp[512]  + qa.w*rp[768]
            + qb.x*rp[1024] + qb.y*rp[1280] + qb.z*rp[1536] + qb.w*rp[1792];
    if (v > best)  { best  = v; bi = i; }
    if (v < worst) { worst = v; wi = i; }
  }
  int c = (-worst > best) ? (64+wi) : bi;
  code[h*LTOT + l] = c;

  // ballot stable rank within wave
  const int lane = t & 63, w = t >> 6;
  u64 mask = ~0ull;
  #pragma unroll
  for (int bit=0; bit<7; bit++){
    u64 bset = __ballot((c>>bit)&1);
    mask &= ((c>>bit)&1) ? bset : ~bset;
  }
  int rin = __popcll(mask & ((lane==0)?0ull:(~0ull >> (64-lane))));
  int cnt = __popcll(mask);

  __shared__ int wh[4][NBUCK];
  ((int*)wh)[t] = 0; ((int*)wh)[t+256] = 0;
  __syncthreads();
  if (rin == 0) wh[w][c] = cnt;        // one leader per (wave, bucket)
  __syncthreads();
  int r = rin;
  for (int ww=0; ww<w; ww++) r += wh[ww][c];
  lrank[h*LTOT + l] = r;
  if (t < NBUCK) hist[(h*NSEG+seg)*NBUCK + t] = wh[0][t]+wh[1][t]+wh[2][t]+wh[3][t];
}

// ---------------- bucket/segment prefix scan (parallel block scan) ----------------
__global__ __launch_bounds__(128) void k_scan(const int* __restrict__ hist,
    int* __restrict__ segoff)
{
  const int h = blockIdx.x, b = threadIdx.x;
  int run = 0;
  #pragma unroll 8
  for (int s=0; s<NSEG; s++) run += hist[(h*NSEG+s)*NBUCK + b];
  // exclusive scan over 128 buckets: shfl scan per wave + LDS carry
  int v = run;
  #pragma unroll
  for (int off=1; off<64; off<<=1){
    int u = __shfl_up(v, off);
    if ((b & 63) >= off) v += u;
  }
  __shared__ int sc[128];
  sc[b] = v;
  __syncthreads();
  int excl = v - run + ((b >= 64) ? sc[63] : 0);
  int run2 = excl;
  for (int s=0; s<NSEG; s++){
    segoff[(h*NSEG+s)*NBUCK + b] = run2;
    run2 += hist[(h*NSEG+s)*NBUCK + b];
  }
}

// ---------------- scatter: sorted position ----------------
__global__ __launch_bounds__(256) void k_scatter(const int* __restrict__ code,
    const int* __restrict__ lrank, const int* __restrict__ segoff,
    int* __restrict__ spos)
{
  const int h = blockIdx.y, seg = blockIdx.x, t = threadIdx.x;
  const int l = seg*256 + t;
  int c = code[h*LTOT + l];
  int r = segoff[(h*NSEG+seg)*NBUCK + c] + lrank[h*LTOT + l];
  spos[h*LTOT + r] = l;
}

// ---------------- chunked attention, MFMA flash-style, static safe-max ----------------
// Keys are unit-normalized => score d = q.khat <= |q|. m = |q|*1.01 is a safe
// static max: no online rescaling, no cross-lane max. lse = m + log(sum) is
// mathematically identical to logsumexp.
__global__ __launch_bounds__(576) void k_attn(const float* __restrict__ xe,
    const float* __restrict__ ye, const int* __restrict__ spos,
    float* __restrict__ ret_u, float* __restrict__ bs_u)
{
  __shared__ int spos_l[432];
  __shared__ float qn[CHU];                   // |q| * 1.01
  __shared__ __align__(16) u16 Klds[432*8];   // normalized keys, bf16
  __shared__ __align__(16) u16 Qlds[144*8];   // raw queries, bf16
  __shared__ __align__(16) u16 VT[32*VTS];    // V^T: [e][key]

  const int t = threadIdx.x;
  const int k = blockIdx.x, h = blockIdx.y;

  // phase 1: gather keys/queries, normalize K, pack bf16
  if (t < 432){
    int region = (t < CHU) ? 0 : (t < 2*CHU) ? 1 : 2;
    int i = t - region*CHU;
    int ck = (k + ((region==1)? -1 : (region==2)? 1 : 0)) & (NCHUNK-1);
    int pos = spos[h*LTOT + ck*CHU + i];
    spos_l[t] = pos;
    const float4* xr = (const float4*)(xe + pos*8);
    float4 a = xr[0], b = xr[1];
    float n2 = a.x*a.x+a.y*a.y+a.z*a.z+a.w*a.w
             + b.x*b.x+b.y*b.y+b.z*b.z+b.w*b.w;
    if (region==0){
      uint4 qpk;
      qpk.x = pkbf(a.x,a.y); qpk.y = pkbf(a.z,a.w);
      qpk.z = pkbf(b.x,b.y); qpk.w = pkbf(b.z,b.w);
      *(uint4*)(Qlds + t*8) = qpk;
      qn[t] = sqrtf(n2)*1.01f + 1e-6f;
    }
    float sc = 1.0f / fmaxf(sqrtf(n2), 5e-5f);
    uint4 kpk;
    kpk.x = pkbf(a.x*sc,a.y*sc); kpk.y = pkbf(a.z*sc,a.w*sc);
    kpk.z = pkbf(b.x*sc,b.y*sc); kpk.w = pkbf(b.z*sc,b.w*sc);
    *(uint4*)(Klds + t*8) = kpk;
  }
  __syncthreads();

  // phase 2: stage V^T bf16 — 432 threads, each: 2 keys x 16 elems
  if (t < 432){
    int p = t >> 1, hf = t & 1;
    int posA = spos_l[2*p], posB = spos_l[2*p+1];
    const float4* ya = (const float4*)(ye + posA*32);
    const float4* yb = (const float4*)(ye + posB*32);
    #pragma unroll
    for (int e4=0; e4<4; e4++){
      float4 va = ya[hf*4+e4], vb = yb[hf*4+e4];
      int e = hf*16 + e4*4;
      *(u32*)&VT[(e+0)*VTS + 2*p] = pkbf(va.x, vb.x);
      *(u32*)&VT[(e+1)*VTS + 2*p] = pkbf(va.y, vb.y);
      *(u32*)&VT[(e+2)*VTS + 2*p] = pkbf(va.z, vb.z);
      *(u32*)&VT[(e+3)*VTS + 2*p] = pkbf(va.w, vb.w);
    }
  }
  __syncthreads();

  // main: wave wv owns query tile wv (16 queries); loop 27 key tiles
  const int lane = t & 63;
  const int wv = t >> 6;          // 0..8
  const int q = lane & 15;
  const int quad = lane >> 4;

  const short4v zs = {0,0,0,0};
  short4v bq = zs;
  if (quad < 2) bq = *(const short4v*)(Qlds + (wv*16+q)*8 + quad*4);
  const float m = qn[wv*16+q];

  f32x4 o0 = {0.f,0.f,0.f,0.f}, o1 = {0.f,0.f,0.f,0.f};
  float s = 0.f;

  for (int kt=0; kt<27; kt++){
    short4v av = zs;
    if (quad < 2) av = *(const short4v*)(Klds + (kt*16+q)*8 + quad*4);
    f32x4 zc = {0.f,0.f,0.f,0.f};
    f32x4 st = __builtin_amdgcn_mfma_f32_16x16x16bf16_1k(av, bq, zc, 0,0,0);

    float p0 = __expf(st[0]-m), p1 = __expf(st[1]-m);
    float p2 = __expf(st[2]-m), p3 = __expf(st[3]-m);
    s += (p0+p1)+(p2+p3);

    union { u32 u[2]; short4v s4; } pk;
    pk.u[0] = pkbf(p0,p1);
    pk.u[1] = pkbf(p2,p3);

    short4v va0 = *(const short4v*)(&VT[ q    *VTS + kt*16 + quad*4]);
    short4v va1 = *(const short4v*)(&VT[(q+16)*VTS + kt*16 + quad*4]);
    o0 = __builtin_amdgcn_mfma_f32_16x16x16bf16_1k(va0, pk.s4, o0, 0,0,0);
    o1 = __builtin_amdgcn_mfma_f32_16x16x16bf16_1k(va1, pk.s4, o1, 0,0,0);
  }

  float stot = s;
  stot += __shfl_xor(stot, 16);
  stot += __shfl_xor(stot, 32);
  float inv = 1.0f / stot;

  // scatter directly to UNSORTED position, e-major layout [e][h][l]
  const int pos = spos_l[wv*16 + q];
  #pragma unroll
  for (int r=0; r<4; r++){
    ret_u[(size_t)(quad*4+r)   *(NH*LTOT) + h*LTOT + pos] = o0[r]*inv;
    ret_u[(size_t)(16+quad*4+r)*(NH*LTOT) + h*LTOT + pos] = o1[r]*inv;
  }
  if (lane < 16)
    bs_u[h*LTOT + spos_l[wv*16+lane]] = m + __logf(stot);
}

// ---------------- cross-hash softmax + residual (fully coalesced) ----------------
__global__ __launch_bounds__(256) void k_final(const float* __restrict__ x,
    const float* __restrict__ ret_u, const float* __restrict__ bs_u,
    float* __restrict__ out)
{
  const int l = blockIdx.x*64 + (threadIdx.x & 63);
  const int eg = threadIdx.x >> 6;        // 0..3 -> elems eg*8..eg*8+7
  float bs[NH];
  #pragma unroll
  for (int h=0;h<NH;h++) bs[h] = bs_u[h*LTOT + l];
  float m = fmaxf(fmaxf(bs[0],bs[1]), fmaxf(bs[2],bs[3]));
  float p[NH]; float s = 0.f;
  #pragma unroll
  for (int h=0;h<NH;h++){ p[h] = __expf(bs[h]-m); s += p[h]; }
  float inv = 1.0f/s;
  float o[8];
  #pragma unroll
  for (int e=0;e<8;e++) o[e]=0.f;
  #pragma unroll
  for (int h=0;h<NH;h++){
    float w = p[h]*inv;
    const float* base = ret_u + (size_t)(eg*8)*(NH*LTOT) + h*LTOT + l;
    #pragma unroll
    for (int e=0;e<8;e++) o[e] += w * base[(size_t)e*(NH*LTOT)];
  }
  #pragma unroll
  for (int e=0;e<8;e++){
    int ge = eg*8 + e;
    out[ge*LTOT + l] = o[e] + x[ge*LTOT + l];
  }
}

extern "C" void kernel_launch(void* const* d_in, const int* in_sizes, int n_in,
                              void* d_out, int out_size, void* d_ws, size_t ws_size,
                              hipStream_t stream)
{
  const float* x   = (const float*)d_in[0];
  const float* wm  = (const float*)d_in[1];
  const float* bm  = (const float*)d_in[2];
  const float* wa  = (const float*)d_in[3];
  const float* ba  = (const float*)d_in[4];
  const float* rot = (const float*)d_in[5];
  float* out = (float*)d_out;

  char* ws = (char*)d_ws;
  size_t off = 0;
  auto alloc = [&](size_t bytes)->void*{
    void* p = ws + off;
    off = (off + bytes + 255) & ~(size_t)255;
    return p;
  };
  float* xe     = (float*)alloc((size_t)LTOT*8*4);
  float* ye     = (float*)alloc((size_t)LTOT*32*4);
  int*   code   = (int*)  alloc((size_t)NH*LTOT*4);
  int*   lrank  = (int*)  alloc((size_t)NH*LTOT*4);
  int*   hist   = (int*)  alloc((size_t)NH*NSEG*NBUCK*4);
  int*   segoff = (int*)  alloc((size_t)NH*NSEG*NBUCK*4);
  int*   spos   = (int*)  alloc((size_t)NH*LTOT*4);
  float* bs_u   = (float*)alloc((size_t)NH*LTOT*4);
  float* ret_u  = (float*)alloc((size_t)32*NH*LTOT*4);

  hipLaunchKernelGGL(k_conv,     dim3(12,12,5),    dim3(256), 0, stream, x, wm, bm, wa, ba, xe, ye);
  hipLaunchKernelGGL(k_hashrank, dim3(NSEG,NH),    dim3(256), 0, stream, xe, rot, code, lrank, hist);
  hipLaunchKernelGGL(k_scan,     dim3(NH),         dim3(128), 0, stream, hist, segoff);
  hipLaunchKernelGGL(k_scatter,  dim3(NSEG,NH),    dim3(256), 0, stream, code, lrank, segoff, spos);
  hipLaunchKernelGGL(k_attn,     dim3(NCHUNK,NH),  dim3(576), 0, stream, xe, ye, spos, ret_u, bs_u);
  hipLaunchKernelGGL(k_final,    dim3(576),        dim3(256), 0, stream, x, ret_u, bs_u, out);
}

// Round 4
// 166.040 us; speedup vs baseline: 2.6450x; 1.1106x over previous
//
#include <hip/hip_runtime.h>
#include <hip/hip_bf16.h>
#include <math.h>

#define LTOT 36864      // 192*192
#define NH 4
#define NCHUNK 256
#define CHU 144
#define NBUCK 128
#define NSEG 144        // 36864 / 256
#define HW_ 192
#define VTS 436         // VT lds row stride (u16 units)

typedef unsigned int u32;
typedef unsigned short u16;
typedef unsigned long long u64;
typedef __attribute__((ext_vector_type(4))) short short4v;
typedef __attribute__((ext_vector_type(4))) float f32x4;

__device__ __forceinline__ u32 pkbf(float a, float b){
  union { __hip_bfloat162 h2; u32 u; } cv;
  cv.h2 = __float22bfloat162_rn(float2{a,b});
  return cv.u;
}
__device__ __forceinline__ float bflo(u32 w){ return __uint_as_float(w<<16); }
__device__ __forceinline__ float bfhi(u32 w){ return __uint_as_float(w & 0xffff0000u); }

// ---------------- conv, z-split: z=0 -> 3x3 (32->8, pad1); z=1..4 -> 1x1 (8ch each) ----------------
__global__ __launch_bounds__(256) void k_conv(const float* __restrict__ x,
    const float* __restrict__ wm, const float* __restrict__ bm,
    const float* __restrict__ wa, const float* __restrict__ ba,
    float* __restrict__ xe, float* __restrict__ ye)
{
  __shared__ float xs[32*324];
  const int t = threadIdx.x;
  const int bx = blockIdx.x, by = blockIdx.y, z = blockIdx.z;
  const int tx = t & 15, ty = t >> 4;
  const int gx = bx*16+tx, gy = by*16+ty;
  const int l = gy*HW_+gx;

  if (z == 0){
    for (int idx=t; idx<32*324; idx+=256){
      int ci = idx/324; int rem = idx-ci*324;
      int iy = rem/18;  int ix = rem-iy*18;
      int yy = by*16+iy-1, xx = bx*16+ix-1;
      float v = 0.f;
      if (yy>=0 && yy<HW_ && xx>=0 && xx<HW_) v = x[ci*LTOT + yy*HW_ + xx];
      xs[idx] = v;
    }
    __syncthreads();
    float accm[8];
    #pragma unroll
    for (int co=0;co<8;co++) accm[co] = bm[co];
    const float* xp0 = xs + ty*18 + tx;
    for (int ci=0; ci<32; ci++){
      const float* xp = xp0 + ci*324;
      float x00=xp[0],  x01=xp[1],  x02=xp[2];
      float x10=xp[18], x11=xp[19], x12=xp[20];
      float x20=xp[36], x21=xp[37], x22=xp[38];
      #pragma unroll
      for (int co=0;co<8;co++){
        const float* w = wm + co*288 + ci*9;
        accm[co] += x00*w[0]+x01*w[1]+x02*w[2]
                  + x10*w[3]+x11*w[4]+x12*w[5]
                  + x20*w[6]+x21*w[7]+x22*w[8];
      }
    }
    float4* xp = (float4*)(xe + l*8);
    xp[0] = make_float4(accm[0],accm[1],accm[2],accm[3]);
    xp[1] = make_float4(accm[4],accm[5],accm[6],accm[7]);
  } else {
    const int cb = (z-1)*8;
    float acc[8];
    #pragma unroll
    for (int co=0;co<8;co++) acc[co] = ba[cb+co];
    #pragma unroll 4
    for (int ci=0; ci<32; ci++){
      float xv = x[ci*LTOT + l];
      #pragma unroll
      for (int co=0;co<8;co++) acc[co] += xv * wa[(cb+co)*32 + ci];
    }
    float4* yp = (float4*)(ye + l*32 + cb);
    yp[0] = make_float4(acc[0],acc[1],acc[2],acc[3]);
    yp[1] = make_float4(acc[4],acc[5],acc[6],acc[7]);
  }
}

// ---------------- hash + stable local rank (merged), ballot-based ----------------
__global__ __launch_bounds__(256) void k_hashrank(const float* __restrict__ xe,
    const float* __restrict__ rot, int* __restrict__ code,
    int* __restrict__ lrank, int* __restrict__ hist)
{
  const int h = blockIdx.y, seg = blockIdx.x, t = threadIdx.x;
  const int l = seg*256 + t;
  const float4* qp = (const float4*)(xe + l*8);
  float4 qa = qp[0], qb = qp[1];
  float best = -INFINITY; int bi = 0;
  float worst = INFINITY; int wi = 0;
  for (int i=0; i<64; i++){
    const float* rp = rot + h*64 + i;   // rot[f*256 + h*64 + i]
    float v = qa.x*rp[0]    + qa.y*rp[256]  + qa.z*rp[512]  + qa.w*rp[768]
            + qb.x*rp[1024] + qb.y*rp[1280] + qb.z*rp[1536] + qb.w*rp[1792];
    if (v > best)  { best  = v; bi = i; }
    if (v < worst) { worst = v; wi = i; }
  }
  int c = (-worst > best) ? (64+wi) : bi;
  code[h*LTOT + l] = c;

  const int lane = t & 63, w = t >> 6;
  u64 mask = ~0ull;
  #pragma unroll
  for (int bit=0; bit<7; bit++){
    u64 bset = __ballot((c>>bit)&1);
    mask &= ((c>>bit)&1) ? bset : ~bset;
  }
  int rin = __popcll(mask & ((lane==0)?0ull:(~0ull >> (64-lane))));
  int cnt = __popcll(mask);

  __shared__ int wh[4][NBUCK];
  ((int*)wh)[t] = 0; ((int*)wh)[t+256] = 0;
  __syncthreads();
  if (rin == 0) wh[w][c] = cnt;
  __syncthreads();
  int r = rin;
  for (int ww=0; ww<w; ww++) r += wh[ww][c];
  lrank[h*LTOT + l] = r;
  if (t < NBUCK) hist[(h*NSEG+seg)*NBUCK + t] = wh[0][t]+wh[1][t]+wh[2][t]+wh[3][t];
}

// ---------------- bucket/segment prefix scan ----------------
__global__ __launch_bounds__(128) void k_scan(const int* __restrict__ hist,
    int* __restrict__ segoff)
{
  const int h = blockIdx.x, b = threadIdx.x;
  int run = 0;
  #pragma unroll 8
  for (int s=0; s<NSEG; s++) run += hist[(h*NSEG+s)*NBUCK + b];
  int v = run;
  #pragma unroll
  for (int off=1; off<64; off<<=1){
    int u = __shfl_up(v, off);
    if ((b & 63) >= off) v += u;
  }
  __shared__ int sc[128];
  sc[b] = v;
  __syncthreads();
  int excl = v - run + ((b >= 64) ? sc[63] : 0);
  int run2 = excl;
  for (int s=0; s<NSEG; s++){
    segoff[(h*NSEG+s)*NBUCK + b] = run2;
    run2 += hist[(h*NSEG+s)*NBUCK + b];
  }
}

// ---------------- scatter + materialize sorted bf16 K/Q (32B rows) and V (64B rows) ----------------
__global__ __launch_bounds__(256) void k_scatter(const int* __restrict__ code,
    const int* __restrict__ lrank, const int* __restrict__ segoff,
    const float* __restrict__ xe, const float* __restrict__ ye,
    int* __restrict__ rankof, u16* __restrict__ KQs, u16* __restrict__ Vs)
{
  const int h = blockIdx.y, seg = blockIdx.x, t = threadIdx.x;
  const int l = seg*256 + t;
  int c = code[h*LTOT + l];
  int r = segoff[(h*NSEG+seg)*NBUCK + c] + lrank[h*LTOT + l];
  rankof[h*LTOT + l] = r;

  const float4* xr = (const float4*)(xe + l*8);
  float4 a = xr[0], b = xr[1];
  float n2 = a.x*a.x+a.y*a.y+a.z*a.z+a.w*a.w
           + b.x*b.x+b.y*b.y+b.z*b.z+b.w*b.w;
  float sc = 1.0f / fmaxf(sqrtf(n2), 5e-5f);
  uint4 kq0, kq1;
  kq0.x = pkbf(a.x*sc,a.y*sc); kq0.y = pkbf(a.z*sc,a.w*sc);
  kq0.z = pkbf(b.x*sc,b.y*sc); kq0.w = pkbf(b.z*sc,b.w*sc);
  kq1.x = pkbf(a.x,a.y); kq1.y = pkbf(a.z,a.w);
  kq1.z = pkbf(b.x,b.y); kq1.w = pkbf(b.z,b.w);
  uint4* kqp = (uint4*)(KQs + (size_t)(h*LTOT + r)*16);
  kqp[0] = kq0; kqp[1] = kq1;

  const float4* yr = (const float4*)(ye + l*32);
  uint4* vp = (uint4*)(Vs + (size_t)(h*LTOT + r)*32);
  #pragma unroll
  for (int e4=0; e4<4; e4++){
    float4 v0 = yr[2*e4], v1 = yr[2*e4+1];
    uint4 w;
    w.x = pkbf(v0.x,v0.y); w.y = pkbf(v0.z,v0.w);
    w.z = pkbf(v1.x,v1.y); w.w = pkbf(v1.z,v1.w);
    vp[e4] = w;
  }
}

// ---------------- chunked attention, MFMA flash-style, static safe-max, all-contiguous staging ----------------
__global__ __launch_bounds__(576) void k_attn(const u16* __restrict__ KQs,
    const u16* __restrict__ Vs, u16* __restrict__ ret_s, float* __restrict__ bs_s)
{
  __shared__ __align__(16) u16 Klds[432*8];
  __shared__ __align__(16) u16 Qlds[144*8];
  __shared__ __align__(16) u16 VT[32*VTS];
  __shared__ float qn[CHU];

  const int t = threadIdx.x;
  const int k = blockIdx.x, h = blockIdx.y;
  const int base = ((k+NCHUNK-1)&(NCHUNK-1))*CHU;   // rows base..base+431 (wrap) = chunks k-1,k,k+1

  if (t < 432){
    int rr = base + t; if (rr >= LTOT) rr -= LTOT;
    *(uint4*)(Klds + t*8) = *(const uint4*)(KQs + (size_t)(h*LTOT+rr)*16);
  } else {
    int i = t - 432;
    uint4 qv = *(const uint4*)(KQs + (size_t)(h*LTOT + k*CHU + i)*16 + 8);
    *(uint4*)(Qlds + i*8) = qv;
    float f0=bflo(qv.x), f1=bfhi(qv.x), f2=bflo(qv.y), f3=bfhi(qv.y);
    float f4=bflo(qv.z), f5=bfhi(qv.z), f6=bflo(qv.w), f7=bfhi(qv.w);
    float n2 = f0*f0+f1*f1+f2*f2+f3*f3+f4*f4+f5*f5+f6*f6+f7*f7;
    qn[i] = sqrtf(n2)*1.01f + 1e-6f;
  }
  // V staging: pair p = rows base+2p, base+2p+1 (contiguous after wrap; base,2p even)
  if (t < 432){
    int p = t >> 1, hf = t & 1;
    int rr = base + 2*p; if (rr >= LTOT) rr -= LTOT;
    const uint4* ra = (const uint4*)(Vs + (size_t)(h*LTOT+rr)*32);
    const uint4* rb = (const uint4*)(Vs + (size_t)(h*LTOT+rr+1)*32);
    uint4 A0 = ra[hf*2], A1 = ra[hf*2+1];
    uint4 B0 = rb[hf*2], B1 = rb[hf*2+1];
    u32 aw[8] = {A0.x,A0.y,A0.z,A0.w,A1.x,A1.y,A1.z,A1.w};
    u32 bw[8] = {B0.x,B0.y,B0.z,B0.w,B1.x,B1.y,B1.z,B1.w};
    int ebase = hf*16;
    #pragma unroll
    for (int m=0;m<8;m++){
      u32 al = aw[m]&0xffffu, ah = aw[m]>>16;
      u32 bl = bw[m]&0xffffu, bh = bw[m]>>16;
      *(u32*)&VT[(ebase+2*m  )*VTS + 2*p] = al | (bl<<16);
      *(u32*)&VT[(ebase+2*m+1)*VTS + 2*p] = ah | (bh<<16);
    }
  }
  __syncthreads();

  const int lane = t & 63;
  const int wv = t >> 6;          // 0..8: query tile
  const int q = lane & 15;
  const int quad = lane >> 4;

  const short4v zs = {0,0,0,0};
  short4v bq = zs;
  if (quad < 2) bq = *(const short4v*)(Qlds + (wv*16+q)*8 + quad*4);
  const float m = qn[wv*16+q];

  f32x4 o0 = {0.f,0.f,0.f,0.f}, o1 = {0.f,0.f,0.f,0.f};
  float s = 0.f;

  for (int kt=0; kt<27; kt++){
    short4v av = zs;
    if (quad < 2) av = *(const short4v*)(Klds + (kt*16+q)*8 + quad*4);
    f32x4 zc = {0.f,0.f,0.f,0.f};
    f32x4 st = __builtin_amdgcn_mfma_f32_16x16x16bf16_1k(av, bq, zc, 0,0,0);

    float p0 = __expf(st[0]-m), p1 = __expf(st[1]-m);
    float p2 = __expf(st[2]-m), p3 = __expf(st[3]-m);
    s += (p0+p1)+(p2+p3);

    union { u32 u[2]; short4v s4; } pk;
    pk.u[0] = pkbf(p0,p1);
    pk.u[1] = pkbf(p2,p3);

    short4v va0 = *(const short4v*)(&VT[ q    *VTS + kt*16 + quad*4]);
    short4v va1 = *(const short4v*)(&VT[(q+16)*VTS + kt*16 + quad*4]);
    o0 = __builtin_amdgcn_mfma_f32_16x16x16bf16_1k(va0, pk.s4, o0, 0,0,0);
    o1 = __builtin_amdgcn_mfma_f32_16x16x16bf16_1k(va1, pk.s4, o1, 0,0,0);
  }

  float stot = s;
  stot += __shfl_xor(stot, 16);
  stot += __shfl_xor(stot, 32);
  float inv = 1.0f / stot;

  // coalesced bf16 row store in SORTED order
  const int row = h*LTOT + k*CHU + wv*16 + q;
  u16* rp = ret_s + (size_t)row*32;
  uint2 wA, wB;
  wA.x = pkbf(o0[0]*inv, o0[1]*inv); wA.y = pkbf(o0[2]*inv, o0[3]*inv);
  wB.x = pkbf(o1[0]*inv, o1[1]*inv); wB.y = pkbf(o1[2]*inv, o1[3]*inv);
  *(uint2*)&rp[quad*4]    = wA;
  *(uint2*)&rp[16+quad*4] = wB;
  if (lane < 16)
    bs_s[h*LTOT + k*CHU + wv*16 + lane] = m + __logf(stot);
}

// ---------------- unsort gather + cross-hash softmax + residual ----------------
__global__ __launch_bounds__(256) void k_final(const float* __restrict__ x,
    const int* __restrict__ rankof, const u16* __restrict__ ret_s,
    const float* __restrict__ bs_s, float* __restrict__ out)
{
  const int l = blockIdx.x*256 + threadIdx.x;
  int r[NH]; float bs[NH];
  #pragma unroll
  for (int h=0;h<NH;h++){ r[h] = rankof[h*LTOT + l]; }
  #pragma unroll
  for (int h=0;h<NH;h++){ bs[h] = bs_s[h*LTOT + r[h]]; }
  float m = fmaxf(fmaxf(bs[0],bs[1]), fmaxf(bs[2],bs[3]));
  float p[NH]; float s = 0.f;
  #pragma unroll
  for (int h=0;h<NH;h++){ p[h] = __expf(bs[h]-m); s += p[h]; }
  float inv = 1.0f/s;
  float o[32];
  #pragma unroll
  for (int e=0;e<32;e++) o[e]=0.f;
  #pragma unroll
  for (int h=0;h<NH;h++){
    float w = p[h]*inv;
    const uint4* rp = (const uint4*)(ret_s + (size_t)(h*LTOT + r[h])*32);
    #pragma unroll
    for (int e4=0;e4<4;e4++){
      uint4 v = rp[e4];
      o[e4*8+0] += w*bflo(v.x); o[e4*8+1] += w*bfhi(v.x);
      o[e4*8+2] += w*bflo(v.y); o[e4*8+3] += w*bfhi(v.y);
      o[e4*8+4] += w*bflo(v.z); o[e4*8+5] += w*bfhi(v.z);
      o[e4*8+6] += w*bflo(v.w); o[e4*8+7] += w*bfhi(v.w);
    }
  }
  #pragma unroll
  for (int e=0;e<32;e++) out[e*LTOT + l] = o[e] + x[e*LTOT + l];
}

extern "C" void kernel_launch(void* const* d_in, const int* in_sizes, int n_in,
                              void* d_out, int out_size, void* d_ws, size_t ws_size,
                              hipStream_t stream)
{
  const float* x   = (const float*)d_in[0];
  const float* wm  = (const float*)d_in[1];
  const float* bm  = (const float*)d_in[2];
  const float* wa  = (const float*)d_in[3];
  const float* ba  = (const float*)d_in[4];
  const float* rot = (const float*)d_in[5];
  float* out = (float*)d_out;

  char* ws = (char*)d_ws;
  size_t off = 0;
  auto alloc = [&](size_t bytes)->void*{
    void* p = ws + off;
    off = (off + bytes + 255) & ~(size_t)255;
    return p;
  };
  float* xe     = (float*)alloc((size_t)LTOT*8*4);
  float* ye     = (float*)alloc((size_t)LTOT*32*4);
  int*   code   = (int*)  alloc((size_t)NH*LTOT*4);
  int*   lrank  = (int*)  alloc((size_t)NH*LTOT*4);
  int*   hist   = (int*)  alloc((size_t)NH*NSEG*NBUCK*4);
  int*   segoff = (int*)  alloc((size_t)NH*NSEG*NBUCK*4);
  int*   rankof = (int*)  alloc((size_t)NH*LTOT*4);
  u16*   KQs    = (u16*)  alloc((size_t)NH*LTOT*16*2);
  u16*   Vs     = (u16*)  alloc((size_t)NH*LTOT*32*2);
  u16*   ret_s  = (u16*)  alloc((size_t)NH*LTOT*32*2);
  float* bs_s   = (float*)alloc((size_t)NH*LTOT*4);

  hipLaunchKernelGGL(k_conv,     dim3(12,12,5),    dim3(256), 0, stream, x, wm, bm, wa, ba, xe, ye);
  hipLaunchKernelGGL(k_hashrank, dim3(NSEG,NH),    dim3(256), 0, stream, xe, rot, code, lrank, hist);
  hipLaunchKernelGGL(k_scan,     dim3(NH),         dim3(128), 0, stream, hist, segoff);
  hipLaunchKernelGGL(k_scatter,  dim3(NSEG,NH),    dim3(256), 0, stream, code, lrank, segoff, xe, ye, rankof, KQs, Vs);
  hipLaunchKernelGGL(k_attn,     dim3(NCHUNK,NH),  dim3(576), 0, stream, KQs, Vs, ret_s, bs_s);
  hipLaunchKernelGGL(k_final,    dim3(NSEG),       dim3(256), 0, stream, x, rankof, ret_s, bs_s, out);
}

// Round 5
// 145.111 us; speedup vs baseline: 3.0265x; 1.1442x over previous
//
#include <hip/hip_runtime.h>
#include <hip/hip_bf16.h>
#include <math.h>

#define LTOT 36864      // 192*192
#define NH 4
#define NCHUNK 256
#define CHU 144
#define NBUCK 128
#define NSEG 144        // 36864 / 256
#define HW_ 192
#define VTS 436         // VT lds row stride (u16 units)

typedef unsigned int u32;
typedef unsigned short u16;
typedef unsigned long long u64;
typedef __attribute__((ext_vector_type(4))) short short4v;
typedef __attribute__((ext_vector_type(4))) float f32x4;

__device__ __forceinline__ u32 pkbf(float a, float b){
  union { __hip_bfloat162 h2; u32 u; } cv;
  cv.h2 = __float22bfloat162_rn(float2{a,b});
  return cv.u;
}
__device__ __forceinline__ float bflo(u32 w){ return __uint_as_float(w<<16); }
__device__ __forceinline__ float bfhi(u32 w){ return __uint_as_float(w & 0xffff0000u); }

// ---------------- conv: blocks 0..575 -> 3x3 (16x4 px tile, wave=co-pair, scalar weights);
//                  blocks 576..1151 -> 1x1 (8 co per block-group) ----------------
__global__ __launch_bounds__(256) void k_conv(const float* __restrict__ x,
    const float* __restrict__ wm, const float* __restrict__ bm,
    const float* __restrict__ wa, const float* __restrict__ ba,
    float* __restrict__ xe, float* __restrict__ ye)
{
  __shared__ float xs[32*108];   // 32 ci x 6x18 halo (3x3 path only)
  const int t = threadIdx.x;
  const int id = blockIdx.x;

  if (id < 576){
    const int bx = id % 12, by = id / 12;   // 16-wide x 4-tall tile
    for (int idx=t; idx<3456; idx+=256){
      int ci = idx/108, rem = idx-ci*108;
      int iy = rem/18,  ix = rem-iy*18;
      int yy = by*4+iy-1, xx = bx*16+ix-1;
      float v = 0.f;
      if (yy>=0 && yy<HW_ && xx>=0 && xx<HW_) v = x[ci*LTOT + yy*HW_ + xx];
      xs[idx] = v;
    }
    __syncthreads();
    const int lane = t & 63;
    const int co0 = __builtin_amdgcn_readfirstlane((t>>6)<<1);  // wave-uniform co pair
    const int ix = lane & 15, iy = lane >> 4;
    float a0 = bm[co0], a1 = bm[co0+1];
    const float* xb  = xs + iy*18 + ix;
    const float* w0p = wm + co0*288;
    const float* w1p = w0p + 288;
    for (int ci=0; ci<32; ci++){
      const float* xp = xb + ci*108;
      float x00=xp[0],  x01=xp[1],  x02=xp[2];
      float x10=xp[18], x11=xp[19], x12=xp[20];
      float x20=xp[36], x21=xp[37], x22=xp[38];
      const float* w0 = w0p + ci*9;
      const float* w1 = w1p + ci*9;
      a0 += x00*w0[0]+x01*w0[1]+x02*w0[2]
          + x10*w0[3]+x11*w0[4]+x12*w0[5]
          + x20*w0[6]+x21*w0[7]+x22*w0[8];
      a1 += x00*w1[0]+x01*w1[1]+x02*w1[2]
          + x10*w1[3]+x11*w1[4]+x12*w1[5]
          + x20*w1[6]+x21*w1[7]+x22*w1[8];
    }
    const int l = (by*4+iy)*HW_ + bx*16+ix;
    *(float2*)(xe + l*8 + co0) = float2{a0,a1};
  } else {
    const int zid = id - 576;
    const int cb = (zid/144)*8;
    const int l  = (zid%144)*256 + t;
    float acc[8];
    #pragma unroll
    for (int co=0;co<8;co++) acc[co] = ba[cb+co];
    #pragma unroll 4
    for (int ci=0; ci<32; ci++){
      float xv = x[ci*LTOT + l];
      #pragma unroll
      for (int co=0;co<8;co++) acc[co] += xv * wa[(cb+co)*32 + ci];
    }
    float4* yp = (float4*)(ye + l*32 + cb);
    yp[0] = make_float4(acc[0],acc[1],acc[2],acc[3]);
    yp[1] = make_float4(acc[4],acc[5],acc[6],acc[7]);
  }
}

// ---------------- hash + stable local rank (merged), ballot-based ----------------
__global__ __launch_bounds__(256) void k_hashrank(const float* __restrict__ xe,
    const float* __restrict__ rot, int* __restrict__ code,
    int* __restrict__ lrank, int* __restrict__ hist)
{
  const int h = blockIdx.y, seg = blockIdx.x, t = threadIdx.x;
  const int l = seg*256 + t;
  const float4* qp = (const float4*)(xe + l*8);
  float4 qa = qp[0], qb = qp[1];
  float best = -INFINITY; int bi = 0;
  float worst = INFINITY; int wi = 0;
  for (int i=0; i<64; i++){
    const float* rp = rot + h*64 + i;   // rot[f*256 + h*64 + i]
    float v = qa.x*rp[0]    + qa.y*rp[256]  + qa.z*rp[512]  + qa.w*rp[768]
            + qb.x*rp[1024] + qb.y*rp[1280] + qb.z*rp[1536] + qb.w*rp[1792];
    if (v > best)  { best  = v; bi = i; }
    if (v < worst) { worst = v; wi = i; }
  }
  int c = (-worst > best) ? (64+wi) : bi;
  code[h*LTOT + l] = c;

  const int lane = t & 63, w = t >> 6;
  u64 mask = ~0ull;
  #pragma unroll
  for (int bit=0; bit<7; bit++){
    u64 bset = __ballot((c>>bit)&1);
    mask &= ((c>>bit)&1) ? bset : ~bset;
  }
  int rin = __popcll(mask & ((lane==0)?0ull:(~0ull >> (64-lane))));
  int cnt = __popcll(mask);

  __shared__ int wh[4][NBUCK];
  ((int*)wh)[t] = 0; ((int*)wh)[t+256] = 0;
  __syncthreads();
  if (rin == 0) wh[w][c] = cnt;
  __syncthreads();
  int r = rin;
  for (int ww=0; ww<w; ww++) r += wh[ww][c];
  lrank[h*LTOT + l] = r;
  if (t < NBUCK) hist[(h*NSEG+seg)*NBUCK + t] = wh[0][t]+wh[1][t]+wh[2][t]+wh[3][t];
}

// ---------------- bucket/segment prefix scan: 512 thr, 4 segment-groups, reg-cached ----------------
__global__ __launch_bounds__(512) void k_scan(const int* __restrict__ hist,
    int* __restrict__ segoff)
{
  const int h = blockIdx.x;
  const int b = threadIdx.x & 127, g = threadIdx.x >> 7;   // g: 0..3 -> segs g*36..g*36+35
  int vals[36];
  int sum = 0;
  #pragma unroll
  for (int i=0;i<36;i++){
    vals[i] = hist[(h*NSEG + g*36 + i)*NBUCK + b];
    sum += vals[i];
  }
  __shared__ int ps[4][NBUCK];
  __shared__ int tot[NBUCK];
  __shared__ int scv[NBUCK];
  ps[g][b] = sum;
  __syncthreads();
  if (g == 0){
    int run = 0;
    #pragma unroll
    for (int gg=0; gg<4; gg++){ int tv = ps[gg][b]; ps[gg][b] = run; run += tv; }
    tot[b] = run;
    int v = run;
    #pragma unroll
    for (int off=1; off<64; off<<=1){
      int u = __shfl_up(v, off);
      if ((b & 63) >= off) v += u;
    }
    scv[b] = v;
  }
  __syncthreads();
  int base = scv[b] - tot[b] + ((b >= 64) ? scv[63] : 0);
  int run2 = base + ps[g][b];
  #pragma unroll
  for (int i=0;i<36;i++){
    segoff[(h*NSEG + g*36 + i)*NBUCK + b] = run2;
    run2 += vals[i];
  }
}

// ---------------- scatter + materialize sorted bf16 K/Q (32B rows) and V (64B rows) ----------------
__global__ __launch_bounds__(256) void k_scatter(const int* __restrict__ code,
    const int* __restrict__ lrank, const int* __restrict__ segoff,
    const float* __restrict__ xe, const float* __restrict__ ye,
    int* __restrict__ rankof, u16* __restrict__ KQs, u16* __restrict__ Vs)
{
  const int h = blockIdx.y, seg = blockIdx.x, t = threadIdx.x;
  const int l = seg*256 + t;
  int c = code[h*LTOT + l];
  int r = segoff[(h*NSEG+seg)*NBUCK + c] + lrank[h*LTOT + l];
  rankof[h*LTOT + l] = r;

  const float4* xr = (const float4*)(xe + l*8);
  float4 a = xr[0], b = xr[1];
  float n2 = a.x*a.x+a.y*a.y+a.z*a.z+a.w*a.w
           + b.x*b.x+b.y*b.y+b.z*b.z+b.w*b.w;
  float sc = 1.0f / fmaxf(sqrtf(n2), 5e-5f);
  uint4 kq0, kq1;
  kq0.x = pkbf(a.x*sc,a.y*sc); kq0.y = pkbf(a.z*sc,a.w*sc);
  kq0.z = pkbf(b.x*sc,b.y*sc); kq0.w = pkbf(b.z*sc,b.w*sc);
  kq1.x = pkbf(a.x,a.y); kq1.y = pkbf(a.z,a.w);
  kq1.z = pkbf(b.x,b.y); kq1.w = pkbf(b.z,b.w);
  uint4* kqp = (uint4*)(KQs + (size_t)(h*LTOT + r)*16);
  kqp[0] = kq0; kqp[1] = kq1;

  const float4* yr = (const float4*)(ye + l*32);
  uint4* vp = (uint4*)(Vs + (size_t)(h*LTOT + r)*32);
  #pragma unroll
  for (int e4=0; e4<4; e4++){
    float4 v0 = yr[2*e4], v1 = yr[2*e4+1];
    uint4 w;
    w.x = pkbf(v0.x,v0.y); w.y = pkbf(v0.z,v0.w);
    w.z = pkbf(v1.x,v1.y); w.w = pkbf(v1.z,v1.w);
    vp[e4] = w;
  }
}

// ---------------- chunked attention, MFMA flash-style, static safe-max ----------------
__global__ __launch_bounds__(576) void k_attn(const u16* __restrict__ KQs,
    const u16* __restrict__ Vs, u16* __restrict__ ret_s, float* __restrict__ bs_s)
{
  __shared__ __align__(16) u16 Klds[432*8];
  __shared__ __align__(16) u16 Qlds[144*8];
  __shared__ __align__(16) u16 VT[32*VTS];
  __shared__ float qn[CHU];

  const int t = threadIdx.x;
  const int k = blockIdx.x, h = blockIdx.y;
  const int base = ((k+NCHUNK-1)&(NCHUNK-1))*CHU;   // rows base..base+431 (wrap)

  if (t < 432){
    int rr = base + t; if (rr >= LTOT) rr -= LTOT;
    *(uint4*)(Klds + t*8) = *(const uint4*)(KQs + (size_t)(h*LTOT+rr)*16);
  } else {
    int i = t - 432;
    uint4 qv = *(const uint4*)(KQs + (size_t)(h*LTOT + k*CHU + i)*16 + 8);
    *(uint4*)(Qlds + i*8) = qv;
    float f0=bflo(qv.x), f1=bfhi(qv.x), f2=bflo(qv.y), f3=bfhi(qv.y);
    float f4=bflo(qv.z), f5=bfhi(qv.z), f6=bflo(qv.w), f7=bfhi(qv.w);
    float n2 = f0*f0+f1*f1+f2*f2+f3*f3+f4*f4+f5*f5+f6*f6+f7*f7;
    qn[i] = sqrtf(n2)*1.01f + 1e-6f;
  }
  if (t < 432){
    int p = t >> 1, hf = t & 1;
    int rr = base + 2*p; if (rr >= LTOT) rr -= LTOT;
    const uint4* ra = (const uint4*)(Vs + (size_t)(h*LTOT+rr)*32);
    const uint4* rb = (const uint4*)(Vs + (size_t)(h*LTOT+rr+1)*32);
    uint4 A0 = ra[hf*2], A1 = ra[hf*2+1];
    uint4 B0 = rb[hf*2], B1 = rb[hf*2+1];
    u32 aw[8] = {A0.x,A0.y,A0.z,A0.w,A1.x,A1.y,A1.z,A1.w};
    u32 bw[8] = {B0.x,B0.y,B0.z,B0.w,B1.x,B1.y,B1.z,B1.w};
    int ebase = hf*16;
    #pragma unroll
    for (int m=0;m<8;m++){
      u32 al = aw[m]&0xffffu, ah = aw[m]>>16;
      u32 bl = bw[m]&0xffffu, bh = bw[m]>>16;
      *(u32*)&VT[(ebase+2*m  )*VTS + 2*p] = al | (bl<<16);
      *(u32*)&VT[(ebase+2*m+1)*VTS + 2*p] = ah | (bh<<16);
    }
  }
  __syncthreads();

  const int lane = t & 63;
  const int wv = t >> 6;          // 0..8: query tile
  const int q = lane & 15;
  const int quad = lane >> 4;

  const short4v zs = {0,0,0,0};
  short4v bq = zs;
  if (quad < 2) bq = *(const short4v*)(Qlds + (wv*16+q)*8 + quad*4);
  const float m = qn[wv*16+q];

  f32x4 o0 = {0.f,0.f,0.f,0.f}, o1 = {0.f,0.f,0.f,0.f};
  float s = 0.f;

  for (int kt=0; kt<27; kt++){
    short4v av = zs;
    if (quad < 2) av = *(const short4v*)(Klds + (kt*16+q)*8 + quad*4);
    f32x4 zc = {0.f,0.f,0.f,0.f};
    f32x4 st = __builtin_amdgcn_mfma_f32_16x16x16bf16_1k(av, bq, zc, 0,0,0);

    float p0 = __expf(st[0]-m), p1 = __expf(st[1]-m);
    float p2 = __expf(st[2]-m), p3 = __expf(st[3]-m);
    s += (p0+p1)+(p2+p3);

    union { u32 u[2]; short4v s4; } pk;
    pk.u[0] = pkbf(p0,p1);
    pk.u[1] = pkbf(p2,p3);

    short4v va0 = *(const short4v*)(&VT[ q    *VTS + kt*16 + quad*4]);
    short4v va1 = *(const short4v*)(&VT[(q+16)*VTS + kt*16 + quad*4]);
    o0 = __builtin_amdgcn_mfma_f32_16x16x16bf16_1k(va0, pk.s4, o0, 0,0,0);
    o1 = __builtin_amdgcn_mfma_f32_16x16x16bf16_1k(va1, pk.s4, o1, 0,0,0);
  }

  float stot = s;
  stot += __shfl_xor(stot, 16);
  stot += __shfl_xor(stot, 32);
  float inv = 1.0f / stot;

  const int row = h*LTOT + k*CHU + wv*16 + q;
  u16* rp = ret_s + (size_t)row*32;
  uint2 wA, wB;
  wA.x = pkbf(o0[0]*inv, o0[1]*inv); wA.y = pkbf(o0[2]*inv, o0[3]*inv);
  wB.x = pkbf(o1[0]*inv, o1[1]*inv); wB.y = pkbf(o1[2]*inv, o1[3]*inv);
  *(uint2*)&rp[quad*4]    = wA;
  *(uint2*)&rp[16+quad*4] = wB;
  if (lane < 16)
    bs_s[h*LTOT + k*CHU + wv*16 + lane] = m + __logf(stot);
}

// ---------------- unsort gather + cross-hash softmax + residual (warp-per-8-elems) ----------------
__global__ __launch_bounds__(256) void k_final(const float* __restrict__ x,
    const int* __restrict__ rankof, const u16* __restrict__ ret_s,
    const float* __restrict__ bs_s, float* __restrict__ out)
{
  const int l  = blockIdx.x*64 + (threadIdx.x & 63);
  const int eg = threadIdx.x >> 6;        // 0..3 -> elems eg*8..eg*8+7
  int r[NH]; float bs[NH];
  #pragma unroll
  for (int h=0;h<NH;h++) r[h] = rankof[h*LTOT + l];
  #pragma unroll
  for (int h=0;h<NH;h++) bs[h] = bs_s[h*LTOT + r[h]];
  float m = fmaxf(fmaxf(bs[0],bs[1]), fmaxf(bs[2],bs[3]));
  float p[NH]; float s = 0.f;
  #pragma unroll
  for (int h=0;h<NH;h++){ p[h] = __expf(bs[h]-m); s += p[h]; }
  float inv = 1.0f/s;
  float o[8];
  #pragma unroll
  for (int e=0;e<8;e++) o[e]=0.f;
  #pragma unroll
  for (int h=0;h<NH;h++){
    float w = p[h]*inv;
    uint4 v = *(const uint4*)(ret_s + (size_t)(h*LTOT + r[h])*32 + eg*8);
    o[0] += w*bflo(v.x); o[1] += w*bfhi(v.x);
    o[2] += w*bflo(v.y); o[3] += w*bfhi(v.y);
    o[4] += w*bflo(v.z); o[5] += w*bfhi(v.z);
    o[6] += w*bflo(v.w); o[7] += w*bfhi(v.w);
  }
  #pragma unroll
  for (int e=0;e<8;e++){
    int ge = eg*8 + e;
    out[ge*LTOT + l] = o[e] + x[ge*LTOT + l];
  }
}

extern "C" void kernel_launch(void* const* d_in, const int* in_sizes, int n_in,
                              void* d_out, int out_size, void* d_ws, size_t ws_size,
                              hipStream_t stream)
{
  const float* x   = (const float*)d_in[0];
  const float* wm  = (const float*)d_in[1];
  const float* bm  = (const float*)d_in[2];
  const float* wa  = (const float*)d_in[3];
  const float* ba  = (const float*)d_in[4];
  const float* rot = (const float*)d_in[5];
  float* out = (float*)d_out;

  char* ws = (char*)d_ws;
  size_t off = 0;
  auto alloc = [&](size_t bytes)->void*{
    void* p = ws + off;
    off = (off + bytes + 255) & ~(size_t)255;
    return p;
  };
  float* xe     = (float*)alloc((size_t)LTOT*8*4);
  float* ye     = (float*)alloc((size_t)LTOT*32*4);
  int*   code   = (int*)  alloc((size_t)NH*LTOT*4);
  int*   lrank  = (int*)  alloc((size_t)NH*LTOT*4);
  int*   hist   = (int*)  alloc((size_t)NH*NSEG*NBUCK*4);
  int*   segoff = (int*)  alloc((size_t)NH*NSEG*NBUCK*4);
  int*   rankof = (int*)  alloc((size_t)NH*LTOT*4);
  u16*   KQs    = (u16*)  alloc((size_t)NH*LTOT*16*2);
  u16*   Vs     = (u16*)  alloc((size_t)NH*LTOT*32*2);
  u16*   ret_s  = (u16*)  alloc((size_t)NH*LTOT*32*2);
  float* bs_s   = (float*)alloc((size_t)NH*LTOT*4);

  hipLaunchKernelGGL(k_conv,     dim3(1152),       dim3(256), 0, stream, x, wm, bm, wa, ba, xe, ye);
  hipLaunchKernelGGL(k_hashrank, dim3(NSEG,NH),    dim3(256), 0, stream, xe, rot, code, lrank, hist);
  hipLaunchKernelGGL(k_scan,     dim3(NH),         dim3(512), 0, stream, hist, segoff);
  hipLaunchKernelGGL(k_scatter,  dim3(NSEG,NH),    dim3(256), 0, stream, code, lrank, segoff, xe, ye, rankof, KQs, Vs);
  hipLaunchKernelGGL(k_attn,     dim3(NCHUNK,NH),  dim3(576), 0, stream, KQs, Vs, ret_s, bs_s);
  hipLaunchKernelGGL(k_final,    dim3(576),        dim3(256), 0, stream, x, rankof, ret_s, bs_s, out);
}

// Round 6
// 137.542 us; speedup vs baseline: 3.1931x; 1.0550x over previous
//
#include <hip/hip_runtime.h>
#include <hip/hip_bf16.h>
#include <math.h>

#define LTOT 36864      // 192*192
#define NH 4
#define NCHUNK 256
#define CHU 144
#define NBUCK 128
#define NSEG 144        // 36864 / 256
#define HW_ 192
#define VTS 148         // per-region VT row stride (u16), 148*2 % 8 == 0 (b64 aligned)

typedef unsigned int u32;
typedef unsigned short u16;
typedef unsigned long long u64;
typedef __attribute__((ext_vector_type(4))) short short4v;
typedef __attribute__((ext_vector_type(4))) float f32x4;

__device__ __forceinline__ u32 pkbf(float a, float b){
  union { __hip_bfloat162 h2; u32 u; } cv;
  cv.h2 = __float22bfloat162_rn(float2{a,b});
  return cv.u;
}
__device__ __forceinline__ float bflo(u32 w){ return __uint_as_float(w<<16); }
__device__ __forceinline__ float bfhi(u32 w){ return __uint_as_float(w & 0xffff0000u); }

// ---------------- conv: blocks 0..575 -> 3x3 (16x4 px tile, wave=co-pair, scalar weights);
//                  blocks 576..1151 -> 1x1 (8 co per block-group) ----------------
__global__ __launch_bounds__(256) void k_conv(const float* __restrict__ x,
    const float* __restrict__ wm, const float* __restrict__ bm,
    const float* __restrict__ wa, const float* __restrict__ ba,
    float* __restrict__ xe, float* __restrict__ ye)
{
  __shared__ float xs[32*108];   // 32 ci x 6x18 halo (3x3 path only)
  const int t = threadIdx.x;
  const int id = blockIdx.x;

  if (id < 576){
    const int bx = id % 12, by = id / 12;   // 16-wide x 4-tall tile
    for (int idx=t; idx<3456; idx+=256){
      int ci = idx/108, rem = idx-ci*108;
      int iy = rem/18,  ix = rem-iy*18;
      int yy = by*4+iy-1, xx = bx*16+ix-1;
      float v = 0.f;
      if (yy>=0 && yy<HW_ && xx>=0 && xx<HW_) v = x[ci*LTOT + yy*HW_ + xx];
      xs[idx] = v;
    }
    __syncthreads();
    const int lane = t & 63;
    const int co0 = __builtin_amdgcn_readfirstlane((t>>6)<<1);  // wave-uniform co pair
    const int ix = lane & 15, iy = lane >> 4;
    float a0 = bm[co0], a1 = bm[co0+1];
    const float* xb  = xs + iy*18 + ix;
    const float* w0p = wm + co0*288;
    const float* w1p = w0p + 288;
    for (int ci=0; ci<32; ci++){
      const float* xp = xb + ci*108;
      float x00=xp[0],  x01=xp[1],  x02=xp[2];
      float x10=xp[18], x11=xp[19], x12=xp[20];
      float x20=xp[36], x21=xp[37], x22=xp[38];
      const float* w0 = w0p + ci*9;
      const float* w1 = w1p + ci*9;
      a0 += x00*w0[0]+x01*w0[1]+x02*w0[2]
          + x10*w0[3]+x11*w0[4]+x12*w0[5]
          + x20*w0[6]+x21*w0[7]+x22*w0[8];
      a1 += x00*w1[0]+x01*w1[1]+x02*w1[2]
          + x10*w1[3]+x11*w1[4]+x12*w1[5]
          + x20*w1[6]+x21*w1[7]+x22*w1[8];
    }
    const int l = (by*4+iy)*HW_ + bx*16+ix;
    *(float2*)(xe + l*8 + co0) = float2{a0,a1};
  } else {
    const int zid = id - 576;
    const int cb = (zid/144)*8;
    const int l  = (zid%144)*256 + t;
    float acc[8];
    #pragma unroll
    for (int co=0;co<8;co++) acc[co] = ba[cb+co];
    #pragma unroll 4
    for (int ci=0; ci<32; ci++){
      float xv = x[ci*LTOT + l];
      #pragma unroll
      for (int co=0;co<8;co++) acc[co] += xv * wa[(cb+co)*32 + ci];
    }
    float4* yp = (float4*)(ye + l*32 + cb);
    yp[0] = make_float4(acc[0],acc[1],acc[2],acc[3]);
    yp[1] = make_float4(acc[4],acc[5],acc[6],acc[7]);
  }
}

// ---------------- hash + stable local rank (merged), ballot-based ----------------
__global__ __launch_bounds__(256) void k_hashrank(const float* __restrict__ xe,
    const float* __restrict__ rot, int* __restrict__ code,
    int* __restrict__ lrank, int* __restrict__ hist)
{
  const int h = blockIdx.y, seg = blockIdx.x, t = threadIdx.x;
  const int l = seg*256 + t;
  const float4* qp = (const float4*)(xe + l*8);
  float4 qa = qp[0], qb = qp[1];
  float best = -INFINITY; int bi = 0;
  float worst = INFINITY; int wi = 0;
  for (int i=0; i<64; i++){
    const float* rp = rot + h*64 + i;   // rot[f*256 + h*64 + i]
    float v = qa.x*rp[0]    + qa.y*rp[256]  + qa.z*rp[512]  + qa.w*rp[768]
            + qb.x*rp[1024] + qb.y*rp[1280] + qb.z*rp[1536] + qb.w*rp[1792];
    if (v > best)  { best  = v; bi = i; }
    if (v < worst) { worst = v; wi = i; }
  }
  int c = (-worst > best) ? (64+wi) : bi;
  code[h*LTOT + l] = c;

  const int lane = t & 63, w = t >> 6;
  u64 mask = ~0ull;
  #pragma unroll
  for (int bit=0; bit<7; bit++){
    u64 bset = __ballot((c>>bit)&1);
    mask &= ((c>>bit)&1) ? bset : ~bset;
  }
  int rin = __popcll(mask & ((lane==0)?0ull:(~0ull >> (64-lane))));
  int cnt = __popcll(mask);

  __shared__ int wh[4][NBUCK];
  ((int*)wh)[t] = 0; ((int*)wh)[t+256] = 0;
  __syncthreads();
  if (rin == 0) wh[w][c] = cnt;
  __syncthreads();
  int r = rin;
  for (int ww=0; ww<w; ww++) r += wh[ww][c];
  lrank[h*LTOT + l] = r;
  if (t < NBUCK) hist[(h*NSEG+seg)*NBUCK + t] = wh[0][t]+wh[1][t]+wh[2][t]+wh[3][t];
}

// ---------------- bucket/segment prefix scan: 512 thr, 4 segment-groups, reg-cached ----------------
__global__ __launch_bounds__(512) void k_scan(const int* __restrict__ hist,
    int* __restrict__ segoff)
{
  const int h = blockIdx.x;
  const int b = threadIdx.x & 127, g = threadIdx.x >> 7;   // g: 0..3 -> segs g*36..g*36+35
  int vals[36];
  int sum = 0;
  #pragma unroll
  for (int i=0;i<36;i++){
    vals[i] = hist[(h*NSEG + g*36 + i)*NBUCK + b];
    sum += vals[i];
  }
  __shared__ int ps[4][NBUCK];
  __shared__ int tot[NBUCK];
  __shared__ int scv[NBUCK];
  ps[g][b] = sum;
  __syncthreads();
  if (g == 0){
    int run = 0;
    #pragma unroll
    for (int gg=0; gg<4; gg++){ int tv = ps[gg][b]; ps[gg][b] = run; run += tv; }
    tot[b] = run;
    int v = run;
    #pragma unroll
    for (int off=1; off<64; off<<=1){
      int u = __shfl_up(v, off);
      if ((b & 63) >= off) v += u;
    }
    scv[b] = v;
  }
  __syncthreads();
  int base = scv[b] - tot[b] + ((b >= 64) ? scv[63] : 0);
  int run2 = base + ps[g][b];
  #pragma unroll
  for (int i=0;i<36;i++){
    segoff[(h*NSEG + g*36 + i)*NBUCK + b] = run2;
    run2 += vals[i];
  }
}

// ---------------- scatter + materialize sorted bf16 K (16B rows), Q (16B rows), V (64B rows) ----------------
__global__ __launch_bounds__(256) void k_scatter(const int* __restrict__ code,
    const int* __restrict__ lrank, const int* __restrict__ segoff,
    const float* __restrict__ xe, const float* __restrict__ ye,
    int* __restrict__ rankof, u16* __restrict__ Ks, u16* __restrict__ Qs,
    u16* __restrict__ Vs)
{
  const int h = blockIdx.y, seg = blockIdx.x, t = threadIdx.x;
  const int l = seg*256 + t;
  int c = code[h*LTOT + l];
  int r = segoff[(h*NSEG+seg)*NBUCK + c] + lrank[h*LTOT + l];
  rankof[h*LTOT + l] = r;

  const float4* xr = (const float4*)(xe + l*8);
  float4 a = xr[0], b = xr[1];
  float n2 = a.x*a.x+a.y*a.y+a.z*a.z+a.w*a.w
           + b.x*b.x+b.y*b.y+b.z*b.z+b.w*b.w;
  float sc = 1.0f / fmaxf(sqrtf(n2), 5e-5f);
  uint4 kk, qq;
  kk.x = pkbf(a.x*sc,a.y*sc); kk.y = pkbf(a.z*sc,a.w*sc);
  kk.z = pkbf(b.x*sc,b.y*sc); kk.w = pkbf(b.z*sc,b.w*sc);
  qq.x = pkbf(a.x,a.y); qq.y = pkbf(a.z,a.w);
  qq.z = pkbf(b.x,b.y); qq.w = pkbf(b.z,b.w);
  *(uint4*)(Ks + (size_t)(h*LTOT + r)*8) = kk;
  *(uint4*)(Qs + (size_t)(h*LTOT + r)*8) = qq;

  const float4* yr = (const float4*)(ye + l*32);
  uint4* vp = (uint4*)(Vs + (size_t)(h*LTOT + r)*32);
  #pragma unroll
  for (int e4=0; e4<4; e4++){
    float4 v0 = yr[2*e4], v1 = yr[2*e4+1];
    uint4 w;
    w.x = pkbf(v0.x,v0.y); w.y = pkbf(v0.z,v0.w);
    w.z = pkbf(v1.x,v1.y); w.w = pkbf(v1.z,v1.w);
    vp[e4] = w;
  }
}

// ---------------- chunked attention: 5 waves x 2 query-tiles, region-phased staging ----------------
// Static safe-max (keys unit-norm => score <= |q|): partial sums over regions
// are linear, so phase-accumulate o,s across 3 regions with no rescaling.
__global__ __launch_bounds__(320) void k_attn(const u16* __restrict__ Ks,
    const u16* __restrict__ Qs, const u16* __restrict__ Vs,
    u16* __restrict__ ret_s, float* __restrict__ bs_s)
{
  __shared__ __align__(16) u16 Klds[CHU*8];    // current region's keys
  __shared__ __align__(16) u16 Qlds[CHU*8];    // queries (chunk k)
  __shared__ __align__(16) u16 VT[32*VTS];     // current region V^T [e][key]
  __shared__ float qn[CHU];

  const int t = threadIdx.x;
  const int k = blockIdx.x, h = blockIdx.y;

  // stage Q + qn once
  if (t < CHU){
    uint4 qv = *(const uint4*)(Qs + (size_t)(h*LTOT + k*CHU + t)*8);
    *(uint4*)(Qlds + t*8) = qv;
    float f0=bflo(qv.x), f1=bfhi(qv.x), f2=bflo(qv.y), f3=bfhi(qv.y);
    float f4=bflo(qv.z), f5=bfhi(qv.z), f6=bflo(qv.w), f7=bfhi(qv.w);
    float n2 = f0*f0+f1*f1+f2*f2+f3*f3+f4*f4+f5*f5+f6*f6+f7*f7;
    qn[t] = sqrtf(n2)*1.01f + 1e-6f;
  }
  __syncthreads();

  const int lane = t & 63;
  const int wv = t >> 6;                 // 0..4
  const int q = lane & 15;
  const int quad = lane >> 4;
  const int tl0 = 2*wv, tl1 = (2*wv+1 < 9) ? 2*wv+1 : 8;   // wave4 duplicates tile 8

  const short4v zs = {0,0,0,0};
  short4v bq0 = zs, bq1 = zs;
  if (quad < 2){
    bq0 = *(const short4v*)(Qlds + (tl0*16+q)*8 + quad*4);
    bq1 = *(const short4v*)(Qlds + (tl1*16+q)*8 + quad*4);
  }
  const float m0 = qn[tl0*16+q], m1 = qn[tl1*16+q];

  f32x4 o00={0,0,0,0}, o01={0,0,0,0}, o10={0,0,0,0}, o11={0,0,0,0};
  float s0 = 0.f, s1 = 0.f;

  for (int r=0; r<3; r++){
    __syncthreads();     // previous region compute done
    const int gkb = ((k + NCHUNK-1 + r) & (NCHUNK-1)) * CHU;
    if (t < CHU){
      *(uint4*)(Klds + t*8) = *(const uint4*)(Ks + (size_t)(h*LTOT + gkb + t)*8);
    } else if (t >= 176){
      int i = t - 176;              // 0..143
      int p = i >> 1, hf = i & 1;   // pair p: rows 2p,2p+1; hf: elems hf*16..hf*16+15
      const uint4* ra = (const uint4*)(Vs + (size_t)(h*LTOT + gkb + 2*p)*32);
      const uint4* rb = (const uint4*)(Vs + (size_t)(h*LTOT + gkb + 2*p+1)*32);
      uint4 A0 = ra[hf*2], A1 = ra[hf*2+1];
      uint4 B0 = rb[hf*2], B1 = rb[hf*2+1];
      u32 aw[8] = {A0.x,A0.y,A0.z,A0.w,A1.x,A1.y,A1.z,A1.w};
      u32 bw[8] = {B0.x,B0.y,B0.z,B0.w,B1.x,B1.y,B1.z,B1.w};
      int ebase = hf*16;
      #pragma unroll
      for (int m=0;m<8;m++){
        u32 al = aw[m]&0xffffu, ah = aw[m]>>16;
        u32 bl = bw[m]&0xffffu, bh = bw[m]>>16;
        *(u32*)&VT[(ebase+2*m  )*VTS + 2*p] = al | (bl<<16);
        *(u32*)&VT[(ebase+2*m+1)*VTS + 2*p] = ah | (bh<<16);
      }
    }
    __syncthreads();

    #pragma unroll 3
    for (int kt=0; kt<9; kt++){
      short4v av = zs;
      if (quad < 2) av = *(const short4v*)(Klds + (kt*16+q)*8 + quad*4);
      f32x4 zc = {0.f,0.f,0.f,0.f};
      f32x4 stA = __builtin_amdgcn_mfma_f32_16x16x16bf16_1k(av, bq0, zc, 0,0,0);
      f32x4 stB = __builtin_amdgcn_mfma_f32_16x16x16bf16_1k(av, bq1, zc, 0,0,0);

      float pA0 = __expf(stA[0]-m0), pA1 = __expf(stA[1]-m0);
      float pA2 = __expf(stA[2]-m0), pA3 = __expf(stA[3]-m0);
      float pB0 = __expf(stB[0]-m1), pB1 = __expf(stB[1]-m1);
      float pB2 = __expf(stB[2]-m1), pB3 = __expf(stB[3]-m1);
      s0 += (pA0+pA1)+(pA2+pA3);
      s1 += (pB0+pB1)+(pB2+pB3);

      union { u32 u[2]; short4v s4; } pkA, pkB;
      pkA.u[0] = pkbf(pA0,pA1); pkA.u[1] = pkbf(pA2,pA3);
      pkB.u[0] = pkbf(pB0,pB1); pkB.u[1] = pkbf(pB2,pB3);

      short4v va0 = *(const short4v*)(&VT[ q    *VTS + kt*16 + quad*4]);
      short4v va1 = *(const short4v*)(&VT[(q+16)*VTS + kt*16 + quad*4]);
      o00 = __builtin_amdgcn_mfma_f32_16x16x16bf16_1k(va0, pkA.s4, o00, 0,0,0);
      o01 = __builtin_amdgcn_mfma_f32_16x16x16bf16_1k(va1, pkA.s4, o01, 0,0,0);
      o10 = __builtin_amdgcn_mfma_f32_16x16x16bf16_1k(va0, pkB.s4, o10, 0,0,0);
      o11 = __builtin_amdgcn_mfma_f32_16x16x16bf16_1k(va1, pkB.s4, o11, 0,0,0);
    }
  }

  float st0 = s0, st1 = s1;
  st0 += __shfl_xor(st0, 16); st0 += __shfl_xor(st0, 32);
  st1 += __shfl_xor(st1, 16); st1 += __shfl_xor(st1, 32);
  float inv0 = 1.0f/st0, inv1 = 1.0f/st1;

  const int row0 = h*LTOT + k*CHU + tl0*16 + q;
  const int row1 = h*LTOT + k*CHU + tl1*16 + q;
  u16* rp0 = ret_s + (size_t)row0*32;
  u16* rp1 = ret_s + (size_t)row1*32;
  uint2 wA, wB;
  wA.x = pkbf(o00[0]*inv0, o00[1]*inv0); wA.y = pkbf(o00[2]*inv0, o00[3]*inv0);
  wB.x = pkbf(o01[0]*inv0, o01[1]*inv0); wB.y = pkbf(o01[2]*inv0, o01[3]*inv0);
  *(uint2*)&rp0[quad*4]    = wA;
  *(uint2*)&rp0[16+quad*4] = wB;
  wA.x = pkbf(o10[0]*inv1, o10[1]*inv1); wA.y = pkbf(o10[2]*inv1, o10[3]*inv1);
  wB.x = pkbf(o11[0]*inv1, o11[1]*inv1); wB.y = pkbf(o11[2]*inv1, o11[3]*inv1);
  *(uint2*)&rp1[quad*4]    = wA;
  *(uint2*)&rp1[16+quad*4] = wB;
  if (quad == 0){
    bs_s[row0] = m0 + __logf(st0);
    bs_s[row1] = m1 + __logf(st1);
  }
}

// ---------------- unsort gather + cross-hash softmax + residual (warp-per-8-elems) ----------------
__global__ __launch_bounds__(256) void k_final(const float* __restrict__ x,
    const int* __restrict__ rankof, const u16* __restrict__ ret_s,
    const float* __restrict__ bs_s, float* __restrict__ out)
{
  const int l  = blockIdx.x*64 + (threadIdx.x & 63);
  const int eg = threadIdx.x >> 6;        // 0..3 -> elems eg*8..eg*8+7
  int r[NH]; float bs[NH];
  #pragma unroll
  for (int h=0;h<NH;h++) r[h] = rankof[h*LTOT + l];
  #pragma unroll
  for (int h=0;h<NH;h++) bs[h] = bs_s[h*LTOT + r[h]];
  float m = fmaxf(fmaxf(bs[0],bs[1]), fmaxf(bs[2],bs[3]));
  float p[NH]; float s = 0.f;
  #pragma unroll
  for (int h=0;h<NH;h++){ p[h] = __expf(bs[h]-m); s += p[h]; }
  float inv = 1.0f/s;
  float o[8];
  #pragma unroll
  for (int e=0;e<8;e++) o[e]=0.f;
  #pragma unroll
  for (int h=0;h<NH;h++){
    float w = p[h]*inv;
    uint4 v = *(const uint4*)(ret_s + (size_t)(h*LTOT + r[h])*32 + eg*8);
    o[0] += w*bflo(v.x); o[1] += w*bfhi(v.x);
    o[2] += w*bflo(v.y); o[3] += w*bfhi(v.y);
    o[4] += w*bflo(v.z); o[5] += w*bfhi(v.z);
    o[6] += w*bflo(v.w); o[7] += w*bfhi(v.w);
  }
  #pragma unroll
  for (int e=0;e<8;e++){
    int ge = eg*8 + e;
    out[ge*LTOT + l] = o[e] + x[ge*LTOT + l];
  }
}

extern "C" void kernel_launch(void* const* d_in, const int* in_sizes, int n_in,
                              void* d_out, int out_size, void* d_ws, size_t ws_size,
                              hipStream_t stream)
{
  const float* x   = (const float*)d_in[0];
  const float* wm  = (const float*)d_in[1];
  const float* bm  = (const float*)d_in[2];
  const float* wa  = (const float*)d_in[3];
  const float* ba  = (const float*)d_in[4];
  const float* rot = (const float*)d_in[5];
  float* out = (float*)d_out;

  char* ws = (char*)d_ws;
  size_t off = 0;
  auto alloc = [&](size_t bytes)->void*{
    void* p = ws + off;
    off = (off + bytes + 255) & ~(size_t)255;
    return p;
  };
  float* xe     = (float*)alloc((size_t)LTOT*8*4);
  float* ye     = (float*)alloc((size_t)LTOT*32*4);
  int*   code   = (int*)  alloc((size_t)NH*LTOT*4);
  int*   lrank  = (int*)  alloc((size_t)NH*LTOT*4);
  int*   hist   = (int*)  alloc((size_t)NH*NSEG*NBUCK*4);
  int*   segoff = (int*)  alloc((size_t)NH*NSEG*NBUCK*4);
  int*   rankof = (int*)  alloc((size_t)NH*LTOT*4);
  u16*   Ks     = (u16*)  alloc((size_t)NH*LTOT*8*2);
  u16*   Qs     = (u16*)  alloc((size_t)NH*LTOT*8*2);
  u16*   Vs     = (u16*)  alloc((size_t)NH*LTOT*32*2);
  u16*   ret_s  = (u16*)  alloc((size_t)NH*LTOT*32*2);
  float* bs_s   = (float*)alloc((size_t)NH*LTOT*4);

  hipLaunchKernelGGL(k_conv,     dim3(1152),       dim3(256), 0, stream, x, wm, bm, wa, ba, xe, ye);
  hipLaunchKernelGGL(k_hashrank, dim3(NSEG,NH),    dim3(256), 0, stream, xe, rot, code, lrank, hist);
  hipLaunchKernelGGL(k_scan,     dim3(NH),         dim3(512), 0, stream, hist, segoff);
  hipLaunchKernelGGL(k_scatter,  dim3(NSEG,NH),    dim3(256), 0, stream, code, lrank, segoff, xe, ye, rankof, Ks, Qs, Vs);
  hipLaunchKernelGGL(k_attn,     dim3(NCHUNK,NH),  dim3(320), 0, stream, Ks, Qs, Vs, ret_s, bs_s);
  hipLaunchKernelGGL(k_final,    dim3(576),        dim3(256), 0, stream, x, rankof, ret_s, bs_s, out);
}